// Round 6
// baseline (212.639 us; speedup 1.0000x reference)
//
#include <hip/hip_runtime.h>
#include <hip/hip_bf16.h>
#include <cstdint>

typedef __bf16 bf16x8 __attribute__((ext_vector_type(8)));
typedef float f32x4 __attribute__((ext_vector_type(4)));
typedef float f32x16 __attribute__((ext_vector_type(16)));
typedef unsigned int u32;
typedef unsigned short u16;
typedef u32 u32x4 __attribute__((ext_vector_type(4)));

#define AS1 __attribute__((address_space(1)))
#define AS3 __attribute__((address_space(3)))

static __device__ __forceinline__ void gld16(const void* g, void* l) {
  __builtin_amdgcn_global_load_lds((const AS1 u32*)g, (AS3 u32*)l, 16, 0, 0);
}
static __device__ __forceinline__ u16 f2b(float f) {
  return __builtin_bit_cast(u16, __float2bfloat16(f));
}
static __device__ __forceinline__ float b2f(u16 u) {
  return __bfloat162float(__builtin_bit_cast(__hip_bfloat16, u));
}
// one-instruction pack: lo = bf16(a), hi = bf16(b)
static __device__ __forceinline__ u32 cvtpk(float a, float b) {
  u32 r;
  asm("v_cvt_pk_bf16_f32 %0, %1, %2" : "=v"(r) : "v"(a), "v"(b));
  return r;
}

// ---------------- RoPE tables: cos/sin[t][i], t<2048, i<64 ----------------
__global__ void k_tables(float* __restrict__ cost, float* __restrict__ sint) {
  const int idx = blockIdx.x * 256 + threadIdx.x;   // 131072 total
  const int t = idx >> 6, i = idx & 63;
  const float inv = exp2f(-(float)(2 * i) * (13.287712379549449f / 128.0f));
  const float f = (float)t * inv;
  cost[idx] = cosf(f);
  sint[idx] = sinf(f);
}

// ---------------- fp32 -> bf16 convert of x, Wq, Wk, Wv ----------------
__global__ void k_convert(const float* __restrict__ x, const float* __restrict__ wq,
                          const float* __restrict__ wk, const float* __restrict__ wv,
                          u16* __restrict__ xb, u16* __restrict__ wqb,
                          u16* __restrict__ wkb, u16* __restrict__ wvb) {
  for (int i4 = blockIdx.x * blockDim.x + threadIdx.x; i4 < 3670016;
       i4 += gridDim.x * blockDim.x) {
    const int e = i4 * 4;
    const float* s; u16* d;
    if (e < 8388608)        { s = x  + e;              d = xb  + e; }
    else if (e < 12582912)  { int o = e - 8388608;  s = wq + o; d = wqb + o; }
    else if (e < 13631488)  { int o = e - 12582912; s = wk + o; d = wkb + o; }
    else                    { int o = e - 13631488; s = wv + o; d = wvb + o; }
    const float4 v = *(const float4*)s;
    ushort4 o4;
    o4.x = f2b(v.x); o4.y = f2b(v.y); o4.z = f2b(v.z); o4.w = f2b(v.w);
    *(ushort4*)d = o4;
  }
}

// ---------------- fused QKV projection GEMM (bf16 MFMA, m97 structure) ----------------
__global__ __launch_bounds__(256) void k_gemm(
    const u16* __restrict__ xb, const u16* __restrict__ wqb,
    const u16* __restrict__ wkb, const u16* __restrict__ wvb,
    u16* __restrict__ qb, u16* __restrict__ kb, u16* __restrict__ vT) {
  __shared__ __align__(16) char smA[8192];   // [128][32] bf16, source-chunk-swizzled
  __shared__ __align__(16) char smB[8192];
  const int tid = threadIdx.x;
  const int w = tid >> 6, l = tid & 63;
  const int lm = l & 15, g = l >> 4;
  const int m0 = blockIdx.x << 7;
  const int j = blockIdx.y;
  const u16* W; u16* dst; int n0, ldc, vmode;
  if (j < 16)      { W = wqb; dst = qb; n0 = j << 7;        ldc = 2048; vmode = 0; }
  else if (j < 20) { W = wkb; dst = kb; n0 = (j - 16) << 7; ldc = 512;  vmode = 0; }
  else             { W = wvb; dst = vT; n0 = (j - 20) << 7; ldc = 0;    vmode = 1; }

  const int srow = w * 16 + (l >> 2);
  const int scol = l & 3;

  f32x4 acc[4][4];
  #pragma unroll
  for (int a = 0; a < 4; ++a)
    #pragma unroll
    for (int bb = 0; bb < 4; ++bb) { f32x4 zz = {0.f, 0.f, 0.f, 0.f}; acc[a][bb] = zz; }

  const int wm = (w >> 1) << 6, wn = (w & 1) << 6;

  for (int k0 = 0; k0 < 2048; k0 += 32) {
    #pragma unroll
    for (int i = 0; i < 2; ++i) {
      const int r = srow + (i << 6);
      const int sc = (scol ^ (r & 3)) << 3;
      gld16(xb + (m0 + r) * 2048 + k0 + sc, smA + ((i * 4 + w) << 10));
      gld16(W  + (n0 + r) * 2048 + k0 + sc, smB + ((i * 4 + w) << 10));
    }
    __syncthreads();
    bf16x8 af[4], bfr[4];
    #pragma unroll
    for (int mt = 0; mt < 4; ++mt) {
      const int row = wm + mt * 16 + lm;
      af[mt] = *(const bf16x8*)(smA + row * 64 + ((g ^ (row & 3)) << 4));
    }
    #pragma unroll
    for (int nt = 0; nt < 4; ++nt) {
      const int row = wn + nt * 16 + lm;
      bfr[nt] = *(const bf16x8*)(smB + row * 64 + ((g ^ (row & 3)) << 4));
    }
    #pragma unroll
    for (int mt = 0; mt < 4; ++mt)
      #pragma unroll
      for (int nt = 0; nt < 4; ++nt)
        acc[mt][nt] = __builtin_amdgcn_mfma_f32_16x16x32_bf16(af[mt], bfr[nt], acc[mt][nt], 0, 0, 0);
    __syncthreads();
  }

  #pragma unroll
  for (int mt = 0; mt < 4; ++mt) {
    #pragma unroll
    for (int nt = 0; nt < 4; ++nt) {
      const int n = n0 + wn + nt * 16 + lm;
      #pragma unroll
      for (int r = 0; r < 4; ++r) {
        const int m = m0 + wm + mt * 16 + g * 4 + r;
        const u16 hv = f2b(acc[mt][nt][r]);
        if (!vmode) dst[m * ldc + n] = hv;
        else        dst[n * 4096 + m] = hv;
      }
    }
  }
}

// ---------------- RMSNorm + RoPE in-place on q and k ----------------
// q additionally pre-scaled by log2(e)/sqrt(128) so attention skips the scale.
__global__ __launch_bounds__(256) void k_normrope(u16* __restrict__ qb, u16* __restrict__ kb,
                                                  const float* __restrict__ cost,
                                                  const float* __restrict__ sint) {
  const int item = blockIdx.x * 4 + (threadIdx.x >> 6);
  const int l = threadIdx.x & 63;
  u16* p; int tpos; float qs;
  if (item < 65536) { p = qb + item * 128; tpos = (item >> 4) & 2047; qs = 0.12751742f; }
  else { const int ik = item - 65536; p = kb + ik * 128; tpos = (ik >> 2) & 2047; qs = 1.0f; }
  const float f1 = b2f(p[l]);
  const float f2 = b2f(p[l + 64]);
  float ss = f1 * f1 + f2 * f2;
  #pragma unroll
  for (int d = 1; d < 64; d <<= 1) ss += __shfl_xor(ss, d);
  const float rn = rsqrtf(ss * (1.0f / 128.0f) + 1.1920928955078125e-07f);
  const float c = cost[tpos * 64 + l], s = sint[tpos * 64 + l];
  const float x1 = f1 * rn, x2 = f2 * rn;
  p[l]      = f2b((x1 * c + x2 * s) * qs);
  p[l + 64] = f2b((x2 * c - x1 * s) * qs);
}

// ---------------- causal GQA flash attention, 32x32 MFMA, 4-wave blocks ----------------
// grid (512): bid&7 = (b,hkv) -> XCD-local KV; bid>>3 = (tau-slot j, head-sub).
// tau map j<8 ? 15-2j : 2(j-8): longest first + complementary pairing across the
// two dispatch rings -> uniform ~34 rounds/CU. Block = 128 q-rows of one head;
// wave w owns rows tau*128+32w..+31. KVBLK=64 double-buffered (64KB LDS).
__global__ __launch_bounds__(256) void k_attn(
    const u16* __restrict__ qb, const u16* __restrict__ kb,
    const u16* __restrict__ vT, float* __restrict__ out) {
  __shared__ __align__(16) char sK[2][16384];   // [64 kv][256B], chunk16 ^ (row&7)
  __shared__ __align__(16) char sV[2][16384];   // [128 d][128B], chunk16 ^ (row&7)
  const int tid = threadIdx.x;
  const int l = tid & 63;
  const int w = tid >> 6;          // wave -> q sub-tile
  const int lq = l & 31;
  const int hi = l >> 5;

  const int bid = blockIdx.x;
  const int cxc = bid & 7;
  const int bb  = cxc >> 2, hkv = cxc & 3;
  const int gg  = bid >> 3;
  const int jj  = gg >> 2, hsub = gg & 3;
  const int h   = hkv * 4 + hsub;
  const int tau = (jj < 8) ? (15 - 2 * jj) : (2 * (jj - 8));
  const int R   = 2 * tau + 2;

  const u16* kbase = kb + ((size_t)bb * 2048) * 512 + hkv * 128;
  const u16* vbase = vT + ((size_t)(hkv * 128)) * 4096 + (size_t)bb * 2048;
  const u16* qhb   = qb + ((size_t)bb * 2048) * 2048 + h * 128;

  const int krow_t = tid >> 4, kch = tid & 15;   // K: 16 rows/iter, 16 chunks
  const int vrow_t = tid >> 3, vch = tid & 7;    // V: 32 rows/iter, 8 chunks

  const int qabs = tau * 128 + w * 32 + lq;
  const int qmin = tau * 128 + w * 32;

  bf16x8 qf[8];
  {
    const u16* qp = qhb + (size_t)qabs * 2048;
    #pragma unroll
    for (int c = 0; c < 8; ++c) qf[c] = *(const bf16x8*)(qp + c * 16 + hi * 8);
  }
  f32x16 oacc[4], s0, s1;
  #pragma unroll
  for (int dt = 0; dt < 4; ++dt)
    #pragma unroll
    for (int e = 0; e < 16; ++e) oacc[dt][e] = 0.f;
  float m = -1e30f, ll = 0.f;

  // prologue: stage kv-tile 0 into buffer 0 (256 threads, 8 x 16B each)
  #pragma unroll
  for (int u = 0; u < 4; ++u) {
    const int kr = u * 16 + krow_t;
    gld16(kbase + (size_t)kr * 512 + ((kch ^ (kr & 7)) << 3), &sK[0][u * 4096 + w * 1024]);
    const int vr = u * 32 + vrow_t;
    gld16(vbase + (size_t)vr * 4096 + ((vch ^ (vr & 7)) << 3), &sV[0][u * 4096 + w * 1024]);
  }
  __syncthreads();

  int cur = 0;
  for (int r = 0; r < R; ++r) {
    // prefetch next kv-tile into the other buffer
    if (r + 1 < R) {
      const int jb2 = (r + 1) * 64;
      char* dK = sK[cur ^ 1], * dV = sV[cur ^ 1];
      #pragma unroll
      for (int u = 0; u < 4; ++u) {
        const int kr = u * 16 + krow_t;
        gld16(kbase + (size_t)(jb2 + kr) * 512 + ((kch ^ (kr & 7)) << 3), dK + u * 4096 + w * 1024);
        const int vr = u * 32 + vrow_t;
        gld16(vbase + (size_t)vr * 4096 + jb2 + ((vch ^ (vr & 7)) << 3), dV + u * 4096 + w * 1024);
      }
    }

    // ---- QK^T: S^T(64kv x 32q) as two 32x32 subtiles ----
    #pragma unroll
    for (int e = 0; e < 16; ++e) { s0[e] = 0.f; s1[e] = 0.f; }
    const char* sk = sK[cur];
    #pragma unroll
    for (int c = 0; c < 8; ++c) {
      const int ch = ((2 * c + hi) ^ (lq & 7)) << 4;
      const bf16x8 kf0 = *(const bf16x8*)(sk + lq * 256 + ch);
      const bf16x8 kf1 = *(const bf16x8*)(sk + (32 + lq) * 256 + ch);
      s0 = __builtin_amdgcn_mfma_f32_32x32x16_bf16(kf0, qf[c], s0, 0, 0, 0);
      s1 = __builtin_amdgcn_mfma_f32_32x32x16_bf16(kf1, qf[c], s1, 0, 0, 0);
    }

    // ---- online softmax (Q pre-scaled; lane owns q-col lq; partner l^32 other kv) ----
    const int jb = r * 64;
    if (jb + 63 > qmin) {
      #pragma unroll
      for (int e = 0; e < 16; ++e) {
        const int kvl = (e & 3) + ((e >> 2) << 3) + (hi << 2);
        if (jb + kvl > qabs)      s0[e] = -1e30f;
        if (jb + 32 + kvl > qabs) s1[e] = -1e30f;
      }
    }
    // tree max (depth ~5)
    float a0[8];
    #pragma unroll
    for (int k2 = 0; k2 < 8; ++k2)
      a0[k2] = fmaxf(fmaxf(s0[2 * k2], s0[2 * k2 + 1]), fmaxf(s1[2 * k2], s1[2 * k2 + 1]));
    float pmax = fmaxf(fmaxf(fmaxf(a0[0], a0[1]), fmaxf(a0[2], a0[3])),
                       fmaxf(fmaxf(a0[4], a0[5]), fmaxf(a0[6], a0[7])));
    pmax = fmaxf(pmax, __shfl_xor(pmax, 32));
    // defer-max: rescale only on real growth (THR = 8)
    if (!__all(pmax <= m + 8.f)) {
      const float mn = fmaxf(m, pmax);
      const float alpha = exp2f(m - mn);
      ll *= alpha;
      #pragma unroll
      for (int dt = 0; dt < 4; ++dt)
        #pragma unroll
        for (int e = 0; e < 16; ++e) oacc[dt][e] *= alpha;
      m = mn;
    }
    // exp2 + tree sum (4 partials)
    float r0 = 0.f, r1 = 0.f, r2 = 0.f, r3 = 0.f;
    #pragma unroll
    for (int e = 0; e < 16; e += 4) {
      const float p00 = exp2f(s0[e] - m),     p01 = exp2f(s0[e + 1] - m);
      const float p02 = exp2f(s0[e + 2] - m), p03 = exp2f(s0[e + 3] - m);
      const float p10 = exp2f(s1[e] - m),     p11 = exp2f(s1[e + 1] - m);
      const float p12 = exp2f(s1[e + 2] - m), p13 = exp2f(s1[e + 3] - m);
      s0[e] = p00; s0[e + 1] = p01; s0[e + 2] = p02; s0[e + 3] = p03;
      s1[e] = p10; s1[e + 1] = p11; s1[e + 2] = p12; s1[e + 3] = p13;
      r0 += p00 + p01; r1 += p02 + p03; r2 += p10 + p11; r3 += p12 + p13;
    }
    float rs = (r0 + r1) + (r2 + r3);
    rs += __shfl_xor(rs, 32);
    ll += rs;

    // ---- PV: O^T(128d x 32q) += Vt * P^T over 4 kv-chunks of 16 ----
    const char* sv = sV[cur];
    #pragma unroll
    for (int cc = 0; cc < 4; ++cc) {
      const int c8 = (cc & 1) * 8;
      float q0, q1, q2, q3, q4, q5, q6, q7;
      if (cc < 2) { q0=s0[c8+0];q1=s0[c8+1];q2=s0[c8+2];q3=s0[c8+3];q4=s0[c8+4];q5=s0[c8+5];q6=s0[c8+6];q7=s0[c8+7]; }
      else        { q0=s1[c8+0];q1=s1[c8+1];q2=s1[c8+2];q3=s1[c8+3];q4=s1[c8+4];q5=s1[c8+5];q6=s1[c8+6];q7=s1[c8+7]; }
      const u32 pk0 = cvtpk(q0, q1), pk1 = cvtpk(q2, q3);
      const u32 pk2 = cvtpk(q4, q5), pk3 = cvtpk(q6, q7);
      // exchange: hi=0 sends Q1(pk2,pk3) / keeps Q0; hi=1 sends Q0(pk0,pk1) / keeps Q1
      const u32 sd0 = hi ? pk0 : pk2;
      const u32 sd1 = hi ? pk1 : pk3;
      const u32 x0 = (u32)__shfl_xor((int)sd0, 32);
      const u32 x1 = (u32)__shfl_xor((int)sd1, 32);
      u32x4 bw;
      bw.x = hi ? x0 : pk0;
      bw.y = hi ? x1 : pk1;
      bw.z = hi ? pk2 : x0;
      bw.w = hi ? pk3 : x1;
      const bf16x8 pf = __builtin_bit_cast(bf16x8, bw);
      const int ch = ((2 * cc + hi) ^ (lq & 7)) << 4;
      #pragma unroll
      for (int dt = 0; dt < 4; ++dt) {
        const bf16x8 vf = *(const bf16x8*)(sv + (dt * 32 + lq) * 128 + ch);
        oacc[dt] = __builtin_amdgcn_mfma_f32_32x32x16_bf16(vf, pf, oacc[dt], 0, 0, 0);
      }
    }

    __syncthreads();
    cur ^= 1;
  }

  // ---- epilogue: write O ----
  const float inv = 1.0f / ll;
  float* ob = out + ((size_t)(bb * 2048 + qabs)) * 2048 + h * 128;
  #pragma unroll
  for (int dt = 0; dt < 4; ++dt)
    #pragma unroll
    for (int qd = 0; qd < 4; ++qd) {
      float4 o4;
      o4.x = oacc[dt][qd * 4 + 0] * inv;
      o4.y = oacc[dt][qd * 4 + 1] * inv;
      o4.z = oacc[dt][qd * 4 + 2] * inv;
      o4.w = oacc[dt][qd * 4 + 3] * inv;
      *(float4*)(ob + dt * 32 + qd * 8 + hi * 4) = o4;
    }
}

extern "C" void kernel_launch(void* const* d_in, const int* in_sizes, int n_in,
                              void* d_out, int out_size, void* d_ws, size_t ws_size,
                              hipStream_t stream) {
  const float* x  = (const float*)d_in[0];
  const float* wq = (const float*)d_in[1];
  const float* wk = (const float*)d_in[2];
  const float* wv = (const float*)d_in[3];
  float* out = (float*)d_out;
  char* ws = (char*)d_ws;

  float* cost = (float*)(ws);                 // 512 KB
  float* sint = (float*)(ws + 524288);        // 512 KB
  u16* xb  = (u16*)(ws + 1048576);            // 16 MB
  u16* wqb = (u16*)(ws + 17825792);           // 8 MB
  u16* wkb = (u16*)(ws + 26214400);           // 2 MB
  u16* wvb = (u16*)(ws + 28311552);           // 2 MB
  u16* qb  = (u16*)(ws + 30408704);           // 16 MB
  u16* kb  = (u16*)(ws + 47185920);           // 4 MB
  u16* vT  = (u16*)(ws + 51380224);           // 4 MB  -> total 55574528
  if (ws_size < 55574528) return;

  k_tables  <<<dim3(512),   dim3(256), 0, stream>>>(cost, sint);
  k_convert <<<dim3(2048),  dim3(256), 0, stream>>>(x, wq, wk, wv, xb, wqb, wkb, wvb);
  k_gemm    <<<dim3(32, 24), dim3(256), 0, stream>>>(xb, wqb, wkb, wvb, qb, kb, vT);
  k_normrope<<<dim3(20480), dim3(256), 0, stream>>>(qb, kb, cost, sint);
  k_attn    <<<dim3(512),   dim3(256), 0, stream>>>(qb, kb, vT, out);
}

// Round 7
// 199.711 us; speedup vs baseline: 1.0647x; 1.0647x over previous
//
#include <hip/hip_runtime.h>
#include <hip/hip_bf16.h>
#include <cstdint>

typedef __bf16 bf16x8 __attribute__((ext_vector_type(8)));
typedef float f32x4 __attribute__((ext_vector_type(4)));
typedef float f32x16 __attribute__((ext_vector_type(16)));
typedef unsigned int u32;
typedef unsigned short u16;
typedef u32 u32x4 __attribute__((ext_vector_type(4)));

#define AS1 __attribute__((address_space(1)))
#define AS3 __attribute__((address_space(3)))

static __device__ __forceinline__ void gld16(const void* g, void* l) {
  __builtin_amdgcn_global_load_lds((const AS1 u32*)g, (AS3 u32*)l, 16, 0, 0);
}
static __device__ __forceinline__ u16 f2b(float f) {
  return __builtin_bit_cast(u16, __float2bfloat16(f));
}
static __device__ __forceinline__ float b2f(u16 u) {
  return __bfloat162float(__builtin_bit_cast(__hip_bfloat16, u));
}
// one-instruction pack: lo = bf16(a), hi = bf16(b)
static __device__ __forceinline__ u32 cvtpk(float a, float b) {
  u32 r;
  asm("v_cvt_pk_bf16_f32 %0, %1, %2" : "=v"(r) : "v"(a), "v"(b));
  return r;
}

// ---------------- RoPE tables: cos/sin[t][i], t<2048, i<64 ----------------
__global__ void k_tables(float* __restrict__ cost, float* __restrict__ sint) {
  const int idx = blockIdx.x * 256 + threadIdx.x;   // 131072 total
  const int t = idx >> 6, i = idx & 63;
  const float inv = exp2f(-(float)(2 * i) * (13.287712379549449f / 128.0f));
  const float f = (float)t * inv;
  cost[idx] = cosf(f);
  sint[idx] = sinf(f);
}

// ---------------- fp32 -> bf16 convert of x, Wq, Wk, Wv ----------------
__global__ void k_convert(const float* __restrict__ x, const float* __restrict__ wq,
                          const float* __restrict__ wk, const float* __restrict__ wv,
                          u16* __restrict__ xb, u16* __restrict__ wqb,
                          u16* __restrict__ wkb, u16* __restrict__ wvb) {
  for (int i4 = blockIdx.x * blockDim.x + threadIdx.x; i4 < 3670016;
       i4 += gridDim.x * blockDim.x) {
    const int e = i4 * 4;
    const float* s; u16* d;
    if (e < 8388608)        { s = x  + e;              d = xb  + e; }
    else if (e < 12582912)  { int o = e - 8388608;  s = wq + o; d = wqb + o; }
    else if (e < 13631488)  { int o = e - 12582912; s = wk + o; d = wkb + o; }
    else                    { int o = e - 13631488; s = wv + o; d = wvb + o; }
    const float4 v = *(const float4*)s;
    ushort4 o4;
    o4.x = f2b(v.x); o4.y = f2b(v.y); o4.z = f2b(v.z); o4.w = f2b(v.w);
    *(ushort4*)d = o4;
  }
}

// ---------------- fused QKV projection GEMM (bf16 MFMA, m97 structure) ----------------
__global__ __launch_bounds__(256) void k_gemm(
    const u16* __restrict__ xb, const u16* __restrict__ wqb,
    const u16* __restrict__ wkb, const u16* __restrict__ wvb,
    u16* __restrict__ qb, u16* __restrict__ kb, u16* __restrict__ vT) {
  __shared__ __align__(16) char smA[8192];   // [128][32] bf16, source-chunk-swizzled
  __shared__ __align__(16) char smB[8192];
  const int tid = threadIdx.x;
  const int w = tid >> 6, l = tid & 63;
  const int lm = l & 15, g = l >> 4;
  const int m0 = blockIdx.x << 7;
  const int j = blockIdx.y;
  const u16* W; u16* dst; int n0, ldc, vmode;
  if (j < 16)      { W = wqb; dst = qb; n0 = j << 7;        ldc = 2048; vmode = 0; }
  else if (j < 20) { W = wkb; dst = kb; n0 = (j - 16) << 7; ldc = 512;  vmode = 0; }
  else             { W = wvb; dst = vT; n0 = (j - 20) << 7; ldc = 0;    vmode = 1; }

  const int srow = w * 16 + (l >> 2);
  const int scol = l & 3;

  f32x4 acc[4][4];
  #pragma unroll
  for (int a = 0; a < 4; ++a)
    #pragma unroll
    for (int bb = 0; bb < 4; ++bb) { f32x4 zz = {0.f, 0.f, 0.f, 0.f}; acc[a][bb] = zz; }

  const int wm = (w >> 1) << 6, wn = (w & 1) << 6;

  for (int k0 = 0; k0 < 2048; k0 += 32) {
    #pragma unroll
    for (int i = 0; i < 2; ++i) {
      const int r = srow + (i << 6);
      const int sc = (scol ^ (r & 3)) << 3;
      gld16(xb + (m0 + r) * 2048 + k0 + sc, smA + ((i * 4 + w) << 10));
      gld16(W  + (n0 + r) * 2048 + k0 + sc, smB + ((i * 4 + w) << 10));
    }
    __syncthreads();
    bf16x8 af[4], bfr[4];
    #pragma unroll
    for (int mt = 0; mt < 4; ++mt) {
      const int row = wm + mt * 16 + lm;
      af[mt] = *(const bf16x8*)(smA + row * 64 + ((g ^ (row & 3)) << 4));
    }
    #pragma unroll
    for (int nt = 0; nt < 4; ++nt) {
      const int row = wn + nt * 16 + lm;
      bfr[nt] = *(const bf16x8*)(smB + row * 64 + ((g ^ (row & 3)) << 4));
    }
    #pragma unroll
    for (int mt = 0; mt < 4; ++mt)
      #pragma unroll
      for (int nt = 0; nt < 4; ++nt)
        acc[mt][nt] = __builtin_amdgcn_mfma_f32_16x16x32_bf16(af[mt], bfr[nt], acc[mt][nt], 0, 0, 0);
    __syncthreads();
  }

  #pragma unroll
  for (int mt = 0; mt < 4; ++mt) {
    #pragma unroll
    for (int nt = 0; nt < 4; ++nt) {
      const int n = n0 + wn + nt * 16 + lm;
      #pragma unroll
      for (int r = 0; r < 4; ++r) {
        const int m = m0 + wm + mt * 16 + g * 4 + r;
        const u16 hv = f2b(acc[mt][nt][r]);
        if (!vmode) dst[m * ldc + n] = hv;
        else        dst[n * 4096 + m] = hv;
      }
    }
  }
}

// ---------------- RMSNorm + RoPE in-place on q and k ----------------
// q additionally pre-scaled by log2(e)/sqrt(128) so attention skips the scale.
__global__ __launch_bounds__(256) void k_normrope(u16* __restrict__ qb, u16* __restrict__ kb,
                                                  const float* __restrict__ cost,
                                                  const float* __restrict__ sint) {
  const int item = blockIdx.x * 4 + (threadIdx.x >> 6);
  const int l = threadIdx.x & 63;
  u16* p; int tpos; float qs;
  if (item < 65536) { p = qb + item * 128; tpos = (item >> 4) & 2047; qs = 0.12751742f; }
  else { const int ik = item - 65536; p = kb + ik * 128; tpos = (ik >> 2) & 2047; qs = 1.0f; }
  const float f1 = b2f(p[l]);
  const float f2 = b2f(p[l + 64]);
  float ss = f1 * f1 + f2 * f2;
  #pragma unroll
  for (int d = 1; d < 64; d <<= 1) ss += __shfl_xor(ss, d);
  const float rn = rsqrtf(ss * (1.0f / 128.0f) + 1.1920928955078125e-07f);
  const float c = cost[tpos * 64 + l], s = sint[tpos * 64 + l];
  const float x1 = f1 * rn, x2 = f2 * rn;
  p[l]      = f2b((x1 * c + x2 * s) * qs);
  p[l + 64] = f2b((x2 * c - x1 * s) * qs);
}

// ---------------- causal GQA flash attention, 32x32 MFMA, KVBLK=32 ----------------
// grid (1024): bid&7 = (b,hkv) -> XCD-local KV; bid>>3: hsub = &3, jj = >>2 (0..31),
// tau = 31-jj (longest blocks dispatched FIRST -> near-zero tail).
// Block = 64 q-rows (2 waves x 32 q). KVBLK=32 double-buffered: 32 KB LDS ->
// 4-5 blocks/CU co-resident; waves sharing a SIMD come from DIFFERENT blocks
// (independent streams -> latency overlap). Inner math identical to round-4.
__global__ __launch_bounds__(128) void k_attn(
    const u16* __restrict__ qb, const u16* __restrict__ kb,
    const u16* __restrict__ vT, float* __restrict__ out) {
  __shared__ __align__(16) char sK[2][8192];   // [32 kv][256B], chunk16 ^ (row&7)
  __shared__ __align__(16) char sV[2][8192];   // [128 d][64B],  chunk16 ^ (row&3)
  const int tid = threadIdx.x;
  const int l = tid & 63;
  const int w = tid >> 6;          // wave 0/1 -> q offset 32*w
  const int lq = l & 31;
  const int hi = l >> 5;

  const int bid = blockIdx.x;
  const int cxc = bid & 7;
  const int bb  = cxc >> 2, hkv = cxc & 3;
  const int rest = bid >> 3;             // 0..127
  const int hsub = rest & 3, jj = rest >> 2;
  const int h   = hkv * 4 + hsub;
  const int tau = 31 - jj;               // 64-row q-tile index, longest first
  const int R   = 2 * (tau + 1);         // kv-rounds of 32

  const u16* kbase = kb + ((size_t)bb * 2048) * 512 + hkv * 128;
  const u16* vbase = vT + ((size_t)(hkv * 128)) * 4096 + (size_t)bb * 2048;
  const u16* qhb   = qb + ((size_t)bb * 2048) * 2048 + h * 128;

  const int krow_t = tid >> 4, kch = tid & 15;   // K: 8 rows/iter, 16 chunks
  const int vrow_t = tid >> 2, vch = tid & 3;    // V: 32 rows/iter, 4 chunks

  const int qabs = tau * 64 + w * 32 + lq;
  const int qmin = tau * 64 + w * 32;

  bf16x8 qf[8];
  {
    const u16* qp = qhb + (size_t)qabs * 2048;
    #pragma unroll
    for (int c = 0; c < 8; ++c) qf[c] = *(const bf16x8*)(qp + c * 16 + hi * 8);
  }
  f32x16 oacc[4], s0;
  #pragma unroll
  for (int dt = 0; dt < 4; ++dt)
    #pragma unroll
    for (int e = 0; e < 16; ++e) oacc[dt][e] = 0.f;
  float m = -1e30f, ll = 0.f;

  // stage kv-tile jb2 into buffer buf (128 threads x 8 gld16 = 16 KB)
  auto STAGE = [&](int buf, int jb2) {
    #pragma unroll
    for (int u = 0; u < 4; ++u) {
      const int kr = u * 8 + krow_t;
      gld16(kbase + (size_t)(jb2 + kr) * 512 + ((kch ^ (kr & 7)) << 3),
            &sK[buf][u * 2048 + tid * 16]);
      const int vr = u * 32 + vrow_t;
      gld16(vbase + (size_t)vr * 4096 + jb2 + ((vch ^ (vr & 3)) << 3),
            &sV[buf][u * 2048 + tid * 16]);
    }
  };

  STAGE(0, 0);
  __syncthreads();

  int cur = 0;
  for (int r = 0; r < R; ++r) {
    // prefetch next kv-tile into the other buffer
    if (r + 1 < R) STAGE(cur ^ 1, (r + 1) * 32);

    // ---- QK^T: S^T(32kv x 32q) ----
    #pragma unroll
    for (int e = 0; e < 16; ++e) s0[e] = 0.f;
    const char* sk = sK[cur];
    #pragma unroll
    for (int c = 0; c < 8; ++c) {
      const int ch = ((2 * c + hi) ^ (lq & 7)) << 4;
      const bf16x8 kf = *(const bf16x8*)(sk + lq * 256 + ch);
      s0 = __builtin_amdgcn_mfma_f32_32x32x16_bf16(kf, qf[c], s0, 0, 0, 0);
    }

    // ---- online softmax (Q pre-scaled; lane owns q-col lq) ----
    const int jb = r * 32;
    if (jb + 31 > qmin) {
      #pragma unroll
      for (int e = 0; e < 16; ++e) {
        const int kvl = (e & 3) + ((e >> 2) << 3) + (hi << 2);
        if (jb + kvl > qabs) s0[e] = -1e30f;
      }
    }
    // tree max
    float a0[8];
    #pragma unroll
    for (int k2 = 0; k2 < 8; ++k2) a0[k2] = fmaxf(s0[2 * k2], s0[2 * k2 + 1]);
    float pmax = fmaxf(fmaxf(fmaxf(a0[0], a0[1]), fmaxf(a0[2], a0[3])),
                       fmaxf(fmaxf(a0[4], a0[5]), fmaxf(a0[6], a0[7])));
    pmax = fmaxf(pmax, __shfl_xor(pmax, 32));
    // defer-max: rescale only on real growth (THR = 8)
    if (!__all(pmax <= m + 8.f)) {
      const float mn = fmaxf(m, pmax);
      const float alpha = exp2f(m - mn);
      ll *= alpha;
      #pragma unroll
      for (int dt = 0; dt < 4; ++dt)
        #pragma unroll
        for (int e = 0; e < 16; ++e) oacc[dt][e] *= alpha;
      m = mn;
    }
    // exp2 + tree sum
    float r0 = 0.f, r1 = 0.f;
    #pragma unroll
    for (int e = 0; e < 16; e += 4) {
      const float p00 = exp2f(s0[e] - m),     p01 = exp2f(s0[e + 1] - m);
      const float p02 = exp2f(s0[e + 2] - m), p03 = exp2f(s0[e + 3] - m);
      s0[e] = p00; s0[e + 1] = p01; s0[e + 2] = p02; s0[e + 3] = p03;
      r0 += p00 + p01; r1 += p02 + p03;
    }
    float rs = r0 + r1;
    rs += __shfl_xor(rs, 32);
    ll += rs;

    // ---- PV: O^T(128d x 32q) += Vt * P^T over 2 kv-chunks of 16 ----
    const char* sv = sV[cur];
    #pragma unroll
    for (int cc = 0; cc < 2; ++cc) {
      const int c8 = cc * 8;
      const u32 pk0 = cvtpk(s0[c8 + 0], s0[c8 + 1]), pk1 = cvtpk(s0[c8 + 2], s0[c8 + 3]);
      const u32 pk2 = cvtpk(s0[c8 + 4], s0[c8 + 5]), pk3 = cvtpk(s0[c8 + 6], s0[c8 + 7]);
      // exchange: hi=0 sends pk2,pk3 (kv 8..11 of window) / hi=1 sends pk0,pk1 (kv 4..7)
      const u32 sd0 = hi ? pk0 : pk2;
      const u32 sd1 = hi ? pk1 : pk3;
      const u32 x0 = (u32)__shfl_xor((int)sd0, 32);
      const u32 x1 = (u32)__shfl_xor((int)sd1, 32);
      u32x4 bw;
      bw.x = hi ? x0 : pk0;
      bw.y = hi ? x1 : pk1;
      bw.z = hi ? pk2 : x0;
      bw.w = hi ? pk3 : x1;
      const bf16x8 pf = __builtin_bit_cast(bf16x8, bw);
      const int chv = ((2 * cc + hi) ^ (lq & 3)) << 4;
      #pragma unroll
      for (int dt = 0; dt < 4; ++dt) {
        const bf16x8 vf = *(const bf16x8*)(sv + (dt * 32 + lq) * 64 + chv);
        oacc[dt] = __builtin_amdgcn_mfma_f32_32x32x16_bf16(vf, pf, oacc[dt], 0, 0, 0);
      }
    }

    __syncthreads();
    cur ^= 1;
  }

  // ---- epilogue: write O ----
  const float inv = 1.0f / ll;
  float* ob = out + ((size_t)(bb * 2048 + qabs)) * 2048 + h * 128;
  #pragma unroll
  for (int dt = 0; dt < 4; ++dt)
    #pragma unroll
    for (int qd = 0; qd < 4; ++qd) {
      float4 o4;
      o4.x = oacc[dt][qd * 4 + 0] * inv;
      o4.y = oacc[dt][qd * 4 + 1] * inv;
      o4.z = oacc[dt][qd * 4 + 2] * inv;
      o4.w = oacc[dt][qd * 4 + 3] * inv;
      *(float4*)(ob + dt * 32 + qd * 8 + hi * 4) = o4;
    }
}

extern "C" void kernel_launch(void* const* d_in, const int* in_sizes, int n_in,
                              void* d_out, int out_size, void* d_ws, size_t ws_size,
                              hipStream_t stream) {
  const float* x  = (const float*)d_in[0];
  const float* wq = (const float*)d_in[1];
  const float* wk = (const float*)d_in[2];
  const float* wv = (const float*)d_in[3];
  float* out = (float*)d_out;
  char* ws = (char*)d_ws;

  float* cost = (float*)(ws);                 // 512 KB
  float* sint = (float*)(ws + 524288);        // 512 KB
  u16* xb  = (u16*)(ws + 1048576);            // 16 MB
  u16* wqb = (u16*)(ws + 17825792);           // 8 MB
  u16* wkb = (u16*)(ws + 26214400);           // 2 MB
  u16* wvb = (u16*)(ws + 28311552);           // 2 MB
  u16* qb  = (u16*)(ws + 30408704);           // 16 MB
  u16* kb  = (u16*)(ws + 47185920);           // 4 MB
  u16* vT  = (u16*)(ws + 51380224);           // 4 MB  -> total 55574528
  if (ws_size < 55574528) return;

  k_tables  <<<dim3(512),   dim3(256), 0, stream>>>(cost, sint);
  k_convert <<<dim3(2048),  dim3(256), 0, stream>>>(x, wq, wk, wv, xb, wqb, wkb, wvb);
  k_gemm    <<<dim3(32, 24), dim3(256), 0, stream>>>(xb, wqb, wkb, wvb, qb, kb, vT);
  k_normrope<<<dim3(20480), dim3(256), 0, stream>>>(qb, kb, cost, sint);
  k_attn    <<<dim3(1024),  dim3(128), 0, stream>>>(qb, kb, vT, out);
}

// Round 8
// 182.080 us; speedup vs baseline: 1.1678x; 1.0968x over previous
//
#include <hip/hip_runtime.h>
#include <hip/hip_bf16.h>
#include <cstdint>

typedef __bf16 bf16x8 __attribute__((ext_vector_type(8)));
typedef float f32x4 __attribute__((ext_vector_type(4)));
typedef float f32x16 __attribute__((ext_vector_type(16)));
typedef unsigned int u32;
typedef unsigned short u16;
typedef u32 u32x4 __attribute__((ext_vector_type(4)));

#define AS1 __attribute__((address_space(1)))
#define AS3 __attribute__((address_space(3)))

static __device__ __forceinline__ void gld16(const void* g, void* l) {
  __builtin_amdgcn_global_load_lds((const AS1 u32*)g, (AS3 u32*)l, 16, 0, 0);
}
static __device__ __forceinline__ u16 f2b(float f) {
  return __builtin_bit_cast(u16, __float2bfloat16(f));
}
static __device__ __forceinline__ float b2f(u16 u) {
  return __bfloat162float(__builtin_bit_cast(__hip_bfloat16, u));
}
// one-instruction pack: lo = bf16(a), hi = bf16(b)
static __device__ __forceinline__ u32 cvtpk(float a, float b) {
  u32 r;
  asm("v_cvt_pk_bf16_f32 %0, %1, %2" : "=v"(r) : "v"(a), "v"(b));
  return r;
}

// ---------------- RoPE tables: cos/sin[t][i], t<2048, i<64 ----------------
__global__ void k_tables(float* __restrict__ cost, float* __restrict__ sint) {
  const int idx = blockIdx.x * 256 + threadIdx.x;   // 131072 total
  const int t = idx >> 6, i = idx & 63;
  const float inv = exp2f(-(float)(2 * i) * (13.287712379549449f / 128.0f));
  const float f = (float)t * inv;
  cost[idx] = cosf(f);
  sint[idx] = sinf(f);
}

// ---------------- fp32 -> bf16 convert of x, Wq, Wk, Wv ----------------
__global__ void k_convert(const float* __restrict__ x, const float* __restrict__ wq,
                          const float* __restrict__ wk, const float* __restrict__ wv,
                          u16* __restrict__ xb, u16* __restrict__ wqb,
                          u16* __restrict__ wkb, u16* __restrict__ wvb) {
  for (int i4 = blockIdx.x * blockDim.x + threadIdx.x; i4 < 3670016;
       i4 += gridDim.x * blockDim.x) {
    const int e = i4 * 4;
    const float* s; u16* d;
    if (e < 8388608)        { s = x  + e;              d = xb  + e; }
    else if (e < 12582912)  { int o = e - 8388608;  s = wq + o; d = wqb + o; }
    else if (e < 13631488)  { int o = e - 12582912; s = wk + o; d = wkb + o; }
    else                    { int o = e - 13631488; s = wv + o; d = wvb + o; }
    const float4 v = *(const float4*)s;
    ushort4 o4;
    o4.x = f2b(v.x); o4.y = f2b(v.y); o4.z = f2b(v.z); o4.w = f2b(v.w);
    *(ushort4*)d = o4;
  }
}

// ---------------- fused QKV projection GEMM (bf16 MFMA, m97 structure) ----------------
__global__ __launch_bounds__(256) void k_gemm(
    const u16* __restrict__ xb, const u16* __restrict__ wqb,
    const u16* __restrict__ wkb, const u16* __restrict__ wvb,
    u16* __restrict__ qb, u16* __restrict__ kb, u16* __restrict__ vT) {
  __shared__ __align__(16) char smA[8192];   // [128][32] bf16, source-chunk-swizzled
  __shared__ __align__(16) char smB[8192];
  const int tid = threadIdx.x;
  const int w = tid >> 6, l = tid & 63;
  const int lm = l & 15, g = l >> 4;
  const int m0 = blockIdx.x << 7;
  const int j = blockIdx.y;
  const u16* W; u16* dst; int n0, ldc, vmode;
  if (j < 16)      { W = wqb; dst = qb; n0 = j << 7;        ldc = 2048; vmode = 0; }
  else if (j < 20) { W = wkb; dst = kb; n0 = (j - 16) << 7; ldc = 512;  vmode = 0; }
  else             { W = wvb; dst = vT; n0 = (j - 20) << 7; ldc = 0;    vmode = 1; }

  const int srow = w * 16 + (l >> 2);
  const int scol = l & 3;

  f32x4 acc[4][4];
  #pragma unroll
  for (int a = 0; a < 4; ++a)
    #pragma unroll
    for (int bb = 0; bb < 4; ++bb) { f32x4 zz = {0.f, 0.f, 0.f, 0.f}; acc[a][bb] = zz; }

  const int wm = (w >> 1) << 6, wn = (w & 1) << 6;

  for (int k0 = 0; k0 < 2048; k0 += 32) {
    #pragma unroll
    for (int i = 0; i < 2; ++i) {
      const int r = srow + (i << 6);
      const int sc = (scol ^ (r & 3)) << 3;
      gld16(xb + (m0 + r) * 2048 + k0 + sc, smA + ((i * 4 + w) << 10));
      gld16(W  + (n0 + r) * 2048 + k0 + sc, smB + ((i * 4 + w) << 10));
    }
    __syncthreads();
    bf16x8 af[4], bfr[4];
    #pragma unroll
    for (int mt = 0; mt < 4; ++mt) {
      const int row = wm + mt * 16 + lm;
      af[mt] = *(const bf16x8*)(smA + row * 64 + ((g ^ (row & 3)) << 4));
    }
    #pragma unroll
    for (int nt = 0; nt < 4; ++nt) {
      const int row = wn + nt * 16 + lm;
      bfr[nt] = *(const bf16x8*)(smB + row * 64 + ((g ^ (row & 3)) << 4));
    }
    #pragma unroll
    for (int mt = 0; mt < 4; ++mt)
      #pragma unroll
      for (int nt = 0; nt < 4; ++nt)
        acc[mt][nt] = __builtin_amdgcn_mfma_f32_16x16x32_bf16(af[mt], bfr[nt], acc[mt][nt], 0, 0, 0);
    __syncthreads();
  }

  #pragma unroll
  for (int mt = 0; mt < 4; ++mt) {
    #pragma unroll
    for (int nt = 0; nt < 4; ++nt) {
      const int n = n0 + wn + nt * 16 + lm;
      #pragma unroll
      for (int r = 0; r < 4; ++r) {
        const int m = m0 + wm + mt * 16 + g * 4 + r;
        const u16 hv = f2b(acc[mt][nt][r]);
        if (!vmode) dst[m * ldc + n] = hv;
        else        dst[n * 4096 + m] = hv;
      }
    }
  }
}

// ---------------- RMSNorm + RoPE in-place on q and k ----------------
// q additionally pre-scaled by log2(e)/sqrt(128) so attention skips the scale.
// Consequence: attention scores s in [-16.4, 16.4] -> no online max needed.
__global__ __launch_bounds__(256) void k_normrope(u16* __restrict__ qb, u16* __restrict__ kb,
                                                  const float* __restrict__ cost,
                                                  const float* __restrict__ sint) {
  const int item = blockIdx.x * 4 + (threadIdx.x >> 6);
  const int l = threadIdx.x & 63;
  u16* p; int tpos; float qs;
  if (item < 65536) { p = qb + item * 128; tpos = (item >> 4) & 2047; qs = 0.12751742f; }
  else { const int ik = item - 65536; p = kb + ik * 128; tpos = (ik >> 2) & 2047; qs = 1.0f; }
  const float f1 = b2f(p[l]);
  const float f2 = b2f(p[l + 64]);
  float ss = f1 * f1 + f2 * f2;
  #pragma unroll
  for (int d = 1; d < 64; d <<= 1) ss += __shfl_xor(ss, d);
  const float rn = rsqrtf(ss * (1.0f / 128.0f) + 1.1920928955078125e-07f);
  const float c = cost[tpos * 64 + l], s = sint[tpos * 64 + l];
  const float x1 = f1 * rn, x2 = f2 * rn;
  p[l]      = f2b((x1 * c + x2 * s) * qs);
  p[l + 64] = f2b((x2 * c - x1 * s) * qs);
}

// ---------------- causal GQA flash attention, 32x32 MFMA, KVBLK=32, NO-MAX softmax ----
// grid (1024): bid&7 = (b,hkv) -> XCD-local KV; tau = 31-jj (longest first).
// Block = 64 q-rows (2 waves x 32 q). RMS-normed q,k bound |s| <= 16.4, so
// softmax uses fixed m=0: p = exp2(s). No max tree / no cross-half sync /
// no rescale per round; ll merged across halves once at epilogue.
// K LDS [32][256B] chunk^(row&15); V LDS paired rows [64][128B] chunk^(row&7).
__global__ __launch_bounds__(128) void k_attn(
    const u16* __restrict__ qb, const u16* __restrict__ kb,
    const u16* __restrict__ vT, float* __restrict__ out) {
  __shared__ __align__(16) char sK[2][8192];   // [32 kv][256B]
  __shared__ __align__(16) char sV[2][8192];   // [64 rows][128B] = d-paired
  const int tid = threadIdx.x;
  const int l = tid & 63;
  const int w = tid >> 6;          // wave 0/1 -> q offset 32*w
  const int lq = l & 31;
  const int hi = l >> 5;

  const int bid = blockIdx.x;
  const int cxc = bid & 7;
  const int bb  = cxc >> 2, hkv = cxc & 3;
  const int rest = bid >> 3;             // 0..127
  const int hsub = rest & 3, jj = rest >> 2;
  const int h   = hkv * 4 + hsub;
  const int tau = 31 - jj;               // 64-row q-tile index, longest first
  const int R   = 2 * (tau + 1);         // kv-rounds of 32

  const u16* kbase = kb + ((size_t)bb * 2048) * 512 + hkv * 128;
  const u16* vbase = vT + ((size_t)(hkv * 128)) * 4096 + (size_t)bb * 2048;
  const u16* qhb   = qb + ((size_t)bb * 2048) * 2048 + h * 128;

  const int krow_t = tid >> 4, kch = tid & 15;   // K: 8 rows/iter, 16 chunks
  const int vrow_t = tid >> 2, vch = tid & 3;    // V: slot coords

  const int qabs = tau * 64 + w * 32 + lq;
  const int qmin = tau * 64 + w * 32;

  bf16x8 qf[8];
  {
    const u16* qp = qhb + (size_t)qabs * 2048;
    #pragma unroll
    for (int c = 0; c < 8; ++c) qf[c] = *(const bf16x8*)(qp + c * 16 + hi * 8);
  }
  f32x16 oacc[4], s0;
  #pragma unroll
  for (int dt = 0; dt < 4; ++dt)
    #pragma unroll
    for (int e = 0; e < 16; ++e) oacc[dt][e] = 0.f;
  float ll = 0.f;

  // stage kv-tile jb2 into buffer buf (128 threads x 8 gld16 = 16 KB)
  auto STAGE = [&](int buf, int jb2) {
    #pragma unroll
    for (int u = 0; u < 4; ++u) {
      const int kr = u * 8 + krow_t;
      gld16(kbase + (size_t)(jb2 + kr) * 512 + ((kch ^ (kr & 15)) << 3),
            &sK[buf][u * 2048 + tid * 16]);
      // V paired-row layout: slot (R0, C0) holds V[2*R0 + (cp>>2)][8*(cp&3) ..]
      const int R0 = u * 16 + (vrow_t >> 1);          // 0..63
      const int C0 = ((vrow_t & 1) << 2) + vch;       // 0..7
      const int cp = C0 ^ (R0 & 7);
      const int vd = 2 * R0 + (cp >> 2);              // d row 0..127
      gld16(vbase + (size_t)vd * 4096 + jb2 + ((cp & 3) << 3),
            &sV[buf][u * 2048 + tid * 16]);
    }
  };

  STAGE(0, 0);
  __syncthreads();

  int cur = 0;
  for (int r = 0; r < R; ++r) {
    // prefetch next kv-tile into the other buffer
    if (r + 1 < R) STAGE(cur ^ 1, (r + 1) * 32);

    // ---- QK^T: S^T(32kv x 32q) ----
    #pragma unroll
    for (int e = 0; e < 16; ++e) s0[e] = 0.f;
    const char* sk = sK[cur];
    #pragma unroll
    for (int c = 0; c < 8; ++c) {
      const int ch = ((2 * c + hi) ^ (lq & 15)) << 4;
      const bf16x8 kf = *(const bf16x8*)(sk + lq * 256 + ch);
      s0 = __builtin_amdgcn_mfma_f32_32x32x16_bf16(kf, qf[c], s0, 0, 0, 0);
    }

    // ---- no-max softmax: p = exp2(s) directly (|s| <= 16.4 guaranteed) ----
    const int jb = r * 32;
    if (jb + 31 > qmin) {
      #pragma unroll
      for (int e = 0; e < 16; ++e) {
        const int kvl = (e & 3) + ((e >> 2) << 3) + (hi << 2);
        if (jb + kvl > qabs) s0[e] = -1e30f;
      }
    }
    float r0 = 0.f, r1 = 0.f;
    #pragma unroll
    for (int e = 0; e < 16; e += 4) {
      const float p00 = exp2f(s0[e]),     p01 = exp2f(s0[e + 1]);
      const float p02 = exp2f(s0[e + 2]), p03 = exp2f(s0[e + 3]);
      s0[e] = p00; s0[e + 1] = p01; s0[e + 2] = p02; s0[e + 3] = p03;
      r0 += p00 + p01; r1 += p02 + p03;
    }
    ll += r0 + r1;   // per-half partial; cross-half merge at epilogue

    // ---- PV: O^T(128d x 32q) += Vt * P^T over 2 kv-chunks of 16 ----
    const char* sv = sV[cur];
    #pragma unroll
    for (int cc = 0; cc < 2; ++cc) {
      const int c8 = cc * 8;
      const u32 pk0 = cvtpk(s0[c8 + 0], s0[c8 + 1]), pk1 = cvtpk(s0[c8 + 2], s0[c8 + 3]);
      const u32 pk2 = cvtpk(s0[c8 + 4], s0[c8 + 5]), pk3 = cvtpk(s0[c8 + 6], s0[c8 + 7]);
      // exchange: hi=0 sends pk2,pk3 / hi=1 sends pk0,pk1
      const u32 sd0 = hi ? pk0 : pk2;
      const u32 sd1 = hi ? pk1 : pk3;
      const u32 x0 = (u32)__shfl_xor((int)sd0, 32);
      const u32 x1 = (u32)__shfl_xor((int)sd1, 32);
      u32x4 bw;
      bw.x = hi ? x0 : pk0;
      bw.y = hi ? x1 : pk1;
      bw.z = hi ? pk2 : x0;
      bw.w = hi ? pk3 : x1;
      const bf16x8 pf = __builtin_bit_cast(bf16x8, bw);
      #pragma unroll
      for (int dt = 0; dt < 4; ++dt) {
        const int vrow = dt * 16 + (lq >> 1);
        const int cpre = ((lq & 1) << 2) + 2 * cc + hi;
        const int chv = (cpre ^ (vrow & 7)) << 4;
        const bf16x8 vf = *(const bf16x8*)(sv + vrow * 128 + chv);
        oacc[dt] = __builtin_amdgcn_mfma_f32_32x32x16_bf16(vf, pf, oacc[dt], 0, 0, 0);
      }
    }

    __syncthreads();
    cur ^= 1;
  }

  // ---- epilogue: merge ll across halves, write O ----
  ll += __shfl_xor(ll, 32);
  const float inv = 1.0f / ll;
  float* ob = out + ((size_t)(bb * 2048 + qabs)) * 2048 + h * 128;
  #pragma unroll
  for (int dt = 0; dt < 4; ++dt)
    #pragma unroll
    for (int qd = 0; qd < 4; ++qd) {
      float4 o4;
      o4.x = oacc[dt][qd * 4 + 0] * inv;
      o4.y = oacc[dt][qd * 4 + 1] * inv;
      o4.z = oacc[dt][qd * 4 + 2] * inv;
      o4.w = oacc[dt][qd * 4 + 3] * inv;
      *(float4*)(ob + dt * 32 + qd * 8 + hi * 4) = o4;
    }
}

extern "C" void kernel_launch(void* const* d_in, const int* in_sizes, int n_in,
                              void* d_out, int out_size, void* d_ws, size_t ws_size,
                              hipStream_t stream) {
  const float* x  = (const float*)d_in[0];
  const float* wq = (const float*)d_in[1];
  const float* wk = (const float*)d_in[2];
  const float* wv = (const float*)d_in[3];
  float* out = (float*)d_out;
  char* ws = (char*)d_ws;

  float* cost = (float*)(ws);                 // 512 KB
  float* sint = (float*)(ws + 524288);        // 512 KB
  u16* xb  = (u16*)(ws + 1048576);            // 16 MB
  u16* wqb = (u16*)(ws + 17825792);           // 8 MB
  u16* wkb = (u16*)(ws + 26214400);           // 2 MB
  u16* wvb = (u16*)(ws + 28311552);           // 2 MB
  u16* qb  = (u16*)(ws + 30408704);           // 16 MB
  u16* kb  = (u16*)(ws + 47185920);           // 4 MB
  u16* vT  = (u16*)(ws + 51380224);           // 4 MB  -> total 55574528
  if (ws_size < 55574528) return;

  k_tables  <<<dim3(512),   dim3(256), 0, stream>>>(cost, sint);
  k_convert <<<dim3(2048),  dim3(256), 0, stream>>>(x, wq, wk, wv, xb, wqb, wkb, wvb);
  k_gemm    <<<dim3(32, 24), dim3(256), 0, stream>>>(xb, wqb, wkb, wvb, qb, kb, vT);
  k_normrope<<<dim3(20480), dim3(256), 0, stream>>>(qb, kb, cost, sint);
  k_attn    <<<dim3(1024),  dim3(128), 0, stream>>>(qb, kb, vT, out);
}

// Round 9
// 169.434 us; speedup vs baseline: 1.2550x; 1.0746x over previous
//
#include <hip/hip_runtime.h>
#include <hip/hip_bf16.h>
#include <cstdint>

typedef __bf16 bf16x8 __attribute__((ext_vector_type(8)));
typedef float f32x4 __attribute__((ext_vector_type(4)));
typedef float f32x16 __attribute__((ext_vector_type(16)));
typedef unsigned int u32;
typedef unsigned short u16;
typedef u32 u32x4 __attribute__((ext_vector_type(4)));

#define AS1 __attribute__((address_space(1)))
#define AS3 __attribute__((address_space(3)))

static __device__ __forceinline__ void gld16(const void* g, void* l) {
  __builtin_amdgcn_global_load_lds((const AS1 u32*)g, (AS3 u32*)l, 16, 0, 0);
}
static __device__ __forceinline__ u16 f2b(float f) {
  return __builtin_bit_cast(u16, __float2bfloat16(f));
}
static __device__ __forceinline__ float b2f(u16 u) {
  return __bfloat162float(__builtin_bit_cast(__hip_bfloat16, u));
}
// one-instruction pack: lo = bf16(a), hi = bf16(b)
static __device__ __forceinline__ u32 cvtpk(float a, float b) {
  u32 r;
  asm("v_cvt_pk_bf16_f32 %0, %1, %2" : "=v"(r) : "v"(a), "v"(b));
  return r;
}

// ---------------- RoPE tables: cos/sin[t][i], t<2048, i<64 ----------------
__global__ void k_tables(float* __restrict__ cost, float* __restrict__ sint) {
  const int idx = blockIdx.x * 256 + threadIdx.x;   // 131072 total
  const int t = idx >> 6, i = idx & 63;
  const float inv = exp2f(-(float)(2 * i) * (13.287712379549449f / 128.0f));
  const float f = (float)t * inv;
  cost[idx] = cosf(f);
  sint[idx] = sinf(f);
}

// ---------------- fp32 -> bf16 convert of x, Wq, Wk, Wv ----------------
__global__ void k_convert(const float* __restrict__ x, const float* __restrict__ wq,
                          const float* __restrict__ wk, const float* __restrict__ wv,
                          u16* __restrict__ xb, u16* __restrict__ wqb,
                          u16* __restrict__ wkb, u16* __restrict__ wvb) {
  for (int i4 = blockIdx.x * blockDim.x + threadIdx.x; i4 < 3670016;
       i4 += gridDim.x * blockDim.x) {
    const int e = i4 * 4;
    const float* s; u16* d;
    if (e < 8388608)        { s = x  + e;              d = xb  + e; }
    else if (e < 12582912)  { int o = e - 8388608;  s = wq + o; d = wqb + o; }
    else if (e < 13631488)  { int o = e - 12582912; s = wk + o; d = wkb + o; }
    else                    { int o = e - 13631488; s = wv + o; d = wvb + o; }
    const float4 v = *(const float4*)s;
    ushort4 o4;
    o4.x = f2b(v.x); o4.y = f2b(v.y); o4.z = f2b(v.z); o4.w = f2b(v.w);
    *(ushort4*)d = o4;
  }
}

// ---------------- fused QKV projection GEMM (bf16 MFMA, m97 structure) ----------------
__global__ __launch_bounds__(256) void k_gemm(
    const u16* __restrict__ xb, const u16* __restrict__ wqb,
    const u16* __restrict__ wkb, const u16* __restrict__ wvb,
    u16* __restrict__ qb, u16* __restrict__ kb, u16* __restrict__ vT) {
  __shared__ __align__(16) char smA[8192];   // [128][32] bf16, source-chunk-swizzled
  __shared__ __align__(16) char smB[8192];
  const int tid = threadIdx.x;
  const int w = tid >> 6, l = tid & 63;
  const int lm = l & 15, g = l >> 4;
  const int m0 = blockIdx.x << 7;
  const int j = blockIdx.y;
  const u16* W; u16* dst; int n0, ldc, vmode;
  if (j < 16)      { W = wqb; dst = qb; n0 = j << 7;        ldc = 2048; vmode = 0; }
  else if (j < 20) { W = wkb; dst = kb; n0 = (j - 16) << 7; ldc = 512;  vmode = 0; }
  else             { W = wvb; dst = vT; n0 = (j - 20) << 7; ldc = 0;    vmode = 1; }

  const int srow = w * 16 + (l >> 2);
  const int scol = l & 3;

  f32x4 acc[4][4];
  #pragma unroll
  for (int a = 0; a < 4; ++a)
    #pragma unroll
    for (int bb = 0; bb < 4; ++bb) { f32x4 zz = {0.f, 0.f, 0.f, 0.f}; acc[a][bb] = zz; }

  const int wm = (w >> 1) << 6, wn = (w & 1) << 6;

  for (int k0 = 0; k0 < 2048; k0 += 32) {
    #pragma unroll
    for (int i = 0; i < 2; ++i) {
      const int r = srow + (i << 6);
      const int sc = (scol ^ (r & 3)) << 3;
      gld16(xb + (m0 + r) * 2048 + k0 + sc, smA + ((i * 4 + w) << 10));
      gld16(W  + (n0 + r) * 2048 + k0 + sc, smB + ((i * 4 + w) << 10));
    }
    __syncthreads();
    bf16x8 af[4], bfr[4];
    #pragma unroll
    for (int mt = 0; mt < 4; ++mt) {
      const int row = wm + mt * 16 + lm;
      af[mt] = *(const bf16x8*)(smA + row * 64 + ((g ^ (row & 3)) << 4));
    }
    #pragma unroll
    for (int nt = 0; nt < 4; ++nt) {
      const int row = wn + nt * 16 + lm;
      bfr[nt] = *(const bf16x8*)(smB + row * 64 + ((g ^ (row & 3)) << 4));
    }
    #pragma unroll
    for (int mt = 0; mt < 4; ++mt)
      #pragma unroll
      for (int nt = 0; nt < 4; ++nt)
        acc[mt][nt] = __builtin_amdgcn_mfma_f32_16x16x32_bf16(af[mt], bfr[nt], acc[mt][nt], 0, 0, 0);
    __syncthreads();
  }

  #pragma unroll
  for (int mt = 0; mt < 4; ++mt) {
    #pragma unroll
    for (int nt = 0; nt < 4; ++nt) {
      const int n = n0 + wn + nt * 16 + lm;
      #pragma unroll
      for (int r = 0; r < 4; ++r) {
        const int m = m0 + wm + mt * 16 + g * 4 + r;
        const u16 hv = f2b(acc[mt][nt][r]);
        if (!vmode) dst[m * ldc + n] = hv;
        else        dst[n * 4096 + m] = hv;
      }
    }
  }
}

// ---------------- RMSNorm + RoPE in-place on q and k ----------------
// q additionally pre-scaled by log2(e)/sqrt(128) so attention skips the scale.
// Consequence: attention scores s in [-16.4, 16.4] -> no online max needed.
__global__ __launch_bounds__(256) void k_normrope(u16* __restrict__ qb, u16* __restrict__ kb,
                                                  const float* __restrict__ cost,
                                                  const float* __restrict__ sint) {
  const int item = blockIdx.x * 4 + (threadIdx.x >> 6);
  const int l = threadIdx.x & 63;
  u16* p; int tpos; float qs;
  if (item < 65536) { p = qb + item * 128; tpos = (item >> 4) & 2047; qs = 0.12751742f; }
  else { const int ik = item - 65536; p = kb + ik * 128; tpos = (ik >> 2) & 2047; qs = 1.0f; }
  const float f1 = b2f(p[l]);
  const float f2 = b2f(p[l + 64]);
  float ss = f1 * f1 + f2 * f2;
  #pragma unroll
  for (int d = 1; d < 64; d <<= 1) ss += __shfl_xor(ss, d);
  const float rn = rsqrtf(ss * (1.0f / 128.0f) + 1.1920928955078125e-07f);
  const float c = cost[tpos * 64 + l], s = sint[tpos * 64 + l];
  const float x1 = f1 * rn, x2 = f2 * rn;
  p[l]      = f2b((x1 * c + x2 * s) * qs);
  p[l + 64] = f2b((x2 * c - x1 * s) * qs);
}

// ---------------- causal GQA flash attention: no-max softmax + in-register kv-split ----
// grid (1024): bid&7 = (b,hkv) XCD-local; tau = 31-jj (longest first).
// Block = 64 q-rows (2 waves x 32 q). Each wave's kv range [0, (tau+1)*64) is
// split into two INTERLEAVED independent streams A/B of tau+1 rounds (KVBLK=32).
// m=0 softmax makes the merge purely additive: shared oacc (MFMA C-chain),
// ll_A + ll_B at epilogue. Critical path halves to tau+1 double-rounds.
// K LDS [32][256B] chunk^(row&15); V LDS paired rows [64][128B] chunk^(row&7).
__global__ __launch_bounds__(128) void k_attn(
    const u16* __restrict__ qb, const u16* __restrict__ kb,
    const u16* __restrict__ vT, float* __restrict__ out) {
  __shared__ __align__(16) char lds[65536];   // [buf][stream][K 8K | V 8K]
  const int tid = threadIdx.x;
  const int l = tid & 63;
  const int w = tid >> 6;          // wave 0/1 -> q offset 32*w
  const int lq = l & 31;
  const int hi = l >> 5;

  const int bid = blockIdx.x;
  const int cxc = bid & 7;
  const int bb  = cxc >> 2, hkv = cxc & 3;
  const int rest = bid >> 3;             // 0..127
  const int hsub = rest & 3, jj = rest >> 2;
  const int h   = hkv * 4 + hsub;
  const int tau = 31 - jj;               // 64-row q-tile index, longest first
  const int RH  = tau + 1;               // double-rounds (each = 2 kv-tiles of 32)
  const int half = RH * 32;              // stream B kv offset

  const u16* kbase = kb + ((size_t)bb * 2048) * 512 + hkv * 128;
  const u16* vbase = vT + ((size_t)(hkv * 128)) * 4096 + (size_t)bb * 2048;
  const u16* qhb   = qb + ((size_t)bb * 2048) * 2048 + h * 128;

  const int krow_t = tid >> 4, kch = tid & 15;   // K staging coords
  const int vrow_t = tid >> 2, vch = tid & 3;    // V staging coords

  const int qabs = tau * 64 + w * 32 + lq;
  const int qmin = tau * 64 + w * 32;

  bf16x8 qf[8];
  {
    const u16* qp = qhb + (size_t)qabs * 2048;
    #pragma unroll
    for (int c = 0; c < 8; ++c) qf[c] = *(const bf16x8*)(qp + c * 16 + hi * 8);
  }
  f32x16 oacc[4], sA, sB;
  #pragma unroll
  for (int dt = 0; dt < 4; ++dt)
    #pragma unroll
    for (int e = 0; e < 16; ++e) oacc[dt][e] = 0.f;
  float llA = 0.f, llB = 0.f;

  // stage one stream's kv-tile (16 KB: K 8K + V 8K), 128 threads x 8 gld16
  auto STAGE = [&](int buf, int st, int jb2) {
    char* bK = lds + buf * 32768 + st * 16384;
    char* bV = bK + 8192;
    #pragma unroll
    for (int u = 0; u < 4; ++u) {
      const int kr = u * 8 + krow_t;
      gld16(kbase + (size_t)(jb2 + kr) * 512 + ((kch ^ (kr & 15)) << 3),
            bK + u * 2048 + tid * 16);
      // V paired-row layout: slot (R0, C0) holds V[2*R0 + (cp>>2)][8*(cp&3) ..]
      const int R0 = u * 16 + (vrow_t >> 1);          // 0..63
      const int C0 = ((vrow_t & 1) << 2) + vch;       // 0..7
      const int cp = C0 ^ (R0 & 7);
      const int vd = 2 * R0 + (cp >> 2);              // d row 0..127
      gld16(vbase + (size_t)vd * 4096 + jb2 + ((cp & 3) << 3),
            bV + u * 2048 + tid * 16);
    }
  };

  STAGE(0, 0, 0);
  STAGE(0, 1, half);
  __syncthreads();

  int cur = 0;
  for (int r = 0; r < RH; ++r) {
    // prefetch next double-tile into the other buffer
    if (r + 1 < RH) {
      STAGE(cur ^ 1, 0, (r + 1) * 32);
      STAGE(cur ^ 1, 1, half + (r + 1) * 32);
    }

    // ---- QK^T for both streams (independent MFMA chains) ----
    #pragma unroll
    for (int e = 0; e < 16; ++e) { sA[e] = 0.f; sB[e] = 0.f; }
    const char* skA = lds + cur * 32768;
    const char* skB = skA + 16384;
    #pragma unroll
    for (int c = 0; c < 8; ++c) {
      const int ch = ((2 * c + hi) ^ (lq & 15)) << 4;
      const bf16x8 kfA = *(const bf16x8*)(skA + lq * 256 + ch);
      const bf16x8 kfB = *(const bf16x8*)(skB + lq * 256 + ch);
      sA = __builtin_amdgcn_mfma_f32_32x32x16_bf16(kfA, qf[c], sA, 0, 0, 0);
      sB = __builtin_amdgcn_mfma_f32_32x32x16_bf16(kfB, qf[c], sB, 0, 0, 0);
    }

    // ---- no-max softmax: p = exp2(s) (|s| <= 16.4 by RMS-norm bound) ----
    const int jbA = r * 32;
    const int jbB = half + r * 32;
    if (jbA + 31 > qmin) {
      #pragma unroll
      for (int e = 0; e < 16; ++e) {
        const int kvl = (e & 3) + ((e >> 2) << 3) + (hi << 2);
        if (jbA + kvl > qabs) sA[e] = -1e30f;
      }
    }
    if (jbB + 31 > qmin) {
      #pragma unroll
      for (int e = 0; e < 16; ++e) {
        const int kvl = (e & 3) + ((e >> 2) << 3) + (hi << 2);
        if (jbB + kvl > qabs) sB[e] = -1e30f;
      }
    }
    float rA = 0.f, rB = 0.f;
    #pragma unroll
    for (int e = 0; e < 16; e += 4) {
      const float a0 = exp2f(sA[e]),     a1 = exp2f(sA[e + 1]);
      const float a2 = exp2f(sA[e + 2]), a3 = exp2f(sA[e + 3]);
      const float b0 = exp2f(sB[e]),     b1 = exp2f(sB[e + 1]);
      const float b2 = exp2f(sB[e + 2]), b3 = exp2f(sB[e + 3]);
      sA[e] = a0; sA[e + 1] = a1; sA[e + 2] = a2; sA[e + 3] = a3;
      sB[e] = b0; sB[e + 1] = b1; sB[e + 2] = b2; sB[e + 3] = b3;
      rA += (a0 + a1) + (a2 + a3);
      rB += (b0 + b1) + (b2 + b3);
    }
    llA += rA; llB += rB;

    // ---- PV for both streams into shared oacc (additive merge) ----
    const char* svA = skA + 8192;
    const char* svB = skB + 8192;
    #pragma unroll
    for (int cc = 0; cc < 2; ++cc) {
      const int c8 = cc * 8;
      // stream A P-fragments
      const u32 a0 = cvtpk(sA[c8 + 0], sA[c8 + 1]), a1 = cvtpk(sA[c8 + 2], sA[c8 + 3]);
      const u32 a2 = cvtpk(sA[c8 + 4], sA[c8 + 5]), a3 = cvtpk(sA[c8 + 6], sA[c8 + 7]);
      const u32 sdA0 = hi ? a0 : a2, sdA1 = hi ? a1 : a3;
      const u32 xA0 = (u32)__shfl_xor((int)sdA0, 32);
      const u32 xA1 = (u32)__shfl_xor((int)sdA1, 32);
      u32x4 bwA;
      bwA.x = hi ? xA0 : a0;
      bwA.y = hi ? xA1 : a1;
      bwA.z = hi ? a2 : xA0;
      bwA.w = hi ? a3 : xA1;
      const bf16x8 pfA = __builtin_bit_cast(bf16x8, bwA);
      // stream B P-fragments
      const u32 b0 = cvtpk(sB[c8 + 0], sB[c8 + 1]), b1 = cvtpk(sB[c8 + 2], sB[c8 + 3]);
      const u32 b2 = cvtpk(sB[c8 + 4], sB[c8 + 5]), b3 = cvtpk(sB[c8 + 6], sB[c8 + 7]);
      const u32 sdB0 = hi ? b0 : b2, sdB1 = hi ? b1 : b3;
      const u32 xB0 = (u32)__shfl_xor((int)sdB0, 32);
      const u32 xB1 = (u32)__shfl_xor((int)sdB1, 32);
      u32x4 bwB;
      bwB.x = hi ? xB0 : b0;
      bwB.y = hi ? xB1 : b1;
      bwB.z = hi ? b2 : xB0;
      bwB.w = hi ? b3 : xB1;
      const bf16x8 pfB = __builtin_bit_cast(bf16x8, bwB);
      #pragma unroll
      for (int dt = 0; dt < 4; ++dt) {
        const int vrow = dt * 16 + (lq >> 1);
        const int cpre = ((lq & 1) << 2) + 2 * cc + hi;
        const int chv = (cpre ^ (vrow & 7)) << 4;
        const bf16x8 vfA = *(const bf16x8*)(svA + vrow * 128 + chv);
        oacc[dt] = __builtin_amdgcn_mfma_f32_32x32x16_bf16(vfA, pfA, oacc[dt], 0, 0, 0);
      }
      #pragma unroll
      for (int dt = 0; dt < 4; ++dt) {
        const int vrow = dt * 16 + (lq >> 1);
        const int cpre = ((lq & 1) << 2) + 2 * cc + hi;
        const int chv = (cpre ^ (vrow & 7)) << 4;
        const bf16x8 vfB = *(const bf16x8*)(svB + vrow * 128 + chv);
        oacc[dt] = __builtin_amdgcn_mfma_f32_32x32x16_bf16(vfB, pfB, oacc[dt], 0, 0, 0);
      }
    }

    __syncthreads();
    cur ^= 1;
  }

  // ---- epilogue: merge streams + halves, write O ----
  float ll = llA + llB;
  ll += __shfl_xor(ll, 32);
  const float inv = 1.0f / ll;
  float* ob = out + ((size_t)(bb * 2048 + qabs)) * 2048 + h * 128;
  #pragma unroll
  for (int dt = 0; dt < 4; ++dt)
    #pragma unroll
    for (int qd = 0; qd < 4; ++qd) {
      float4 o4;
      o4.x = oacc[dt][qd * 4 + 0] * inv;
      o4.y = oacc[dt][qd * 4 + 1] * inv;
      o4.z = oacc[dt][qd * 4 + 2] * inv;
      o4.w = oacc[dt][qd * 4 + 3] * inv;
      *(float4*)(ob + dt * 32 + qd * 8 + hi * 4) = o4;
    }
}

extern "C" void kernel_launch(void* const* d_in, const int* in_sizes, int n_in,
                              void* d_out, int out_size, void* d_ws, size_t ws_size,
                              hipStream_t stream) {
  const float* x  = (const float*)d_in[0];
  const float* wq = (const float*)d_in[1];
  const float* wk = (const float*)d_in[2];
  const float* wv = (const float*)d_in[3];
  float* out = (float*)d_out;
  char* ws = (char*)d_ws;

  float* cost = (float*)(ws);                 // 512 KB
  float* sint = (float*)(ws + 524288);        // 512 KB
  u16* xb  = (u16*)(ws + 1048576);            // 16 MB
  u16* wqb = (u16*)(ws + 17825792);           // 8 MB
  u16* wkb = (u16*)(ws + 26214400);           // 2 MB
  u16* wvb = (u16*)(ws + 28311552);           // 2 MB
  u16* qb  = (u16*)(ws + 30408704);           // 16 MB
  u16* kb  = (u16*)(ws + 47185920);           // 4 MB
  u16* vT  = (u16*)(ws + 51380224);           // 4 MB  -> total 55574528
  if (ws_size < 55574528) return;

  k_tables  <<<dim3(512),   dim3(256), 0, stream>>>(cost, sint);
  k_convert <<<dim3(2048),  dim3(256), 0, stream>>>(x, wq, wk, wv, xb, wqb, wkb, wvb);
  k_gemm    <<<dim3(32, 24), dim3(256), 0, stream>>>(xb, wqb, wkb, wvb, qb, kb, vT);
  k_normrope<<<dim3(20480), dim3(256), 0, stream>>>(qb, kb, cost, sint);
  k_attn    <<<dim3(1024),  dim3(128), 0, stream>>>(qb, kb, vT, out);
}

// Round 10
// 168.163 us; speedup vs baseline: 1.2645x; 1.0076x over previous
//
#include <hip/hip_runtime.h>
#include <hip/hip_bf16.h>
#include <cstdint>

typedef __bf16 bf16x8 __attribute__((ext_vector_type(8)));
typedef float f32x4 __attribute__((ext_vector_type(4)));
typedef float f32x16 __attribute__((ext_vector_type(16)));
typedef unsigned int u32;
typedef unsigned short u16;
typedef u32 u32x4 __attribute__((ext_vector_type(4)));

#define AS1 __attribute__((address_space(1)))
#define AS3 __attribute__((address_space(3)))

static __device__ __forceinline__ void gld16(const void* g, void* l) {
  __builtin_amdgcn_global_load_lds((const AS1 u32*)g, (AS3 u32*)l, 16, 0, 0);
}
static __device__ __forceinline__ u16 f2b(float f) {
  return __builtin_bit_cast(u16, __float2bfloat16(f));
}
static __device__ __forceinline__ float b2f(u16 u) {
  return __bfloat162float(__builtin_bit_cast(__hip_bfloat16, u));
}
// one-instruction pack: lo = bf16(a), hi = bf16(b)
static __device__ __forceinline__ u32 cvtpk(float a, float b) {
  u32 r;
  asm("v_cvt_pk_bf16_f32 %0, %1, %2" : "=v"(r) : "v"(a), "v"(b));
  return r;
}

// ---------------- RoPE tables: cos/sin[t][i], t<2048, i<64 ----------------
__global__ void k_tables(float* __restrict__ cost, float* __restrict__ sint) {
  const int idx = blockIdx.x * 256 + threadIdx.x;   // 131072 total
  const int t = idx >> 6, i = idx & 63;
  const float inv = exp2f(-(float)(2 * i) * (13.287712379549449f / 128.0f));
  const float f = (float)t * inv;
  cost[idx] = cosf(f);
  sint[idx] = sinf(f);
}

// ---------------- fp32 -> bf16 convert of x, Wq, Wk, Wv ----------------
__global__ void k_convert(const float* __restrict__ x, const float* __restrict__ wq,
                          const float* __restrict__ wk, const float* __restrict__ wv,
                          u16* __restrict__ xb, u16* __restrict__ wqb,
                          u16* __restrict__ wkb, u16* __restrict__ wvb) {
  for (int i4 = blockIdx.x * blockDim.x + threadIdx.x; i4 < 3670016;
       i4 += gridDim.x * blockDim.x) {
    const int e = i4 * 4;
    const float* s; u16* d;
    if (e < 8388608)        { s = x  + e;              d = xb  + e; }
    else if (e < 12582912)  { int o = e - 8388608;  s = wq + o; d = wqb + o; }
    else if (e < 13631488)  { int o = e - 12582912; s = wk + o; d = wkb + o; }
    else                    { int o = e - 13631488; s = wv + o; d = wvb + o; }
    const float4 v = *(const float4*)s;
    ushort4 o4;
    o4.x = f2b(v.x); o4.y = f2b(v.y); o4.z = f2b(v.z); o4.w = f2b(v.w);
    *(ushort4*)d = o4;
  }
}

// ---------------- fused QKV projection GEMM (bf16 MFMA, m97 structure) ----------------
// vT is written with token-index bits 2<->3 swapped (within each 16-token group):
// makes attention's PV B-fragment equal the lane's OWN softmax values (no shfl).
__global__ __launch_bounds__(256) void k_gemm(
    const u16* __restrict__ xb, const u16* __restrict__ wqb,
    const u16* __restrict__ wkb, const u16* __restrict__ wvb,
    u16* __restrict__ qb, u16* __restrict__ kb, u16* __restrict__ vT) {
  __shared__ __align__(16) char smA[8192];   // [128][32] bf16, source-chunk-swizzled
  __shared__ __align__(16) char smB[8192];
  const int tid = threadIdx.x;
  const int w = tid >> 6, l = tid & 63;
  const int lm = l & 15, g = l >> 4;
  const int m0 = blockIdx.x << 7;
  const int j = blockIdx.y;
  const u16* W; u16* dst; int n0, ldc, vmode;
  if (j < 16)      { W = wqb; dst = qb; n0 = j << 7;        ldc = 2048; vmode = 0; }
  else if (j < 20) { W = wkb; dst = kb; n0 = (j - 16) << 7; ldc = 512;  vmode = 0; }
  else             { W = wvb; dst = vT; n0 = (j - 20) << 7; ldc = 0;    vmode = 1; }

  const int srow = w * 16 + (l >> 2);
  const int scol = l & 3;

  f32x4 acc[4][4];
  #pragma unroll
  for (int a = 0; a < 4; ++a)
    #pragma unroll
    for (int bb = 0; bb < 4; ++bb) { f32x4 zz = {0.f, 0.f, 0.f, 0.f}; acc[a][bb] = zz; }

  const int wm = (w >> 1) << 6, wn = (w & 1) << 6;

  for (int k0 = 0; k0 < 2048; k0 += 32) {
    #pragma unroll
    for (int i = 0; i < 2; ++i) {
      const int r = srow + (i << 6);
      const int sc = (scol ^ (r & 3)) << 3;
      gld16(xb + (m0 + r) * 2048 + k0 + sc, smA + ((i * 4 + w) << 10));
      gld16(W  + (n0 + r) * 2048 + k0 + sc, smB + ((i * 4 + w) << 10));
    }
    __syncthreads();
    bf16x8 af[4], bfr[4];
    #pragma unroll
    for (int mt = 0; mt < 4; ++mt) {
      const int row = wm + mt * 16 + lm;
      af[mt] = *(const bf16x8*)(smA + row * 64 + ((g ^ (row & 3)) << 4));
    }
    #pragma unroll
    for (int nt = 0; nt < 4; ++nt) {
      const int row = wn + nt * 16 + lm;
      bfr[nt] = *(const bf16x8*)(smB + row * 64 + ((g ^ (row & 3)) << 4));
    }
    #pragma unroll
    for (int mt = 0; mt < 4; ++mt)
      #pragma unroll
      for (int nt = 0; nt < 4; ++nt)
        acc[mt][nt] = __builtin_amdgcn_mfma_f32_16x16x32_bf16(af[mt], bfr[nt], acc[mt][nt], 0, 0, 0);
    __syncthreads();
  }

  const int gs = ((g & 1) << 1) | (g >> 1);   // token-index bit2<->bit3 swap for vT
  #pragma unroll
  for (int mt = 0; mt < 4; ++mt) {
    #pragma unroll
    for (int nt = 0; nt < 4; ++nt) {
      const int n = n0 + wn + nt * 16 + lm;
      #pragma unroll
      for (int r = 0; r < 4; ++r) {
        const u16 hv = f2b(acc[mt][nt][r]);
        if (!vmode) {
          const int mq = m0 + wm + mt * 16 + g * 4 + r;
          dst[mq * ldc + n] = hv;
        } else {
          const int mv = m0 + wm + mt * 16 + gs * 4 + r;
          dst[n * 4096 + mv] = hv;
        }
      }
    }
  }
}

// ---------------- RMSNorm + RoPE in-place on q and k ----------------
// q additionally pre-scaled by log2(e)/sqrt(128) so attention skips the scale.
// Consequence: attention scores s in [-16.4, 16.4] -> no online max needed.
__global__ __launch_bounds__(256) void k_normrope(u16* __restrict__ qb, u16* __restrict__ kb,
                                                  const float* __restrict__ cost,
                                                  const float* __restrict__ sint) {
  const int item = blockIdx.x * 4 + (threadIdx.x >> 6);
  const int l = threadIdx.x & 63;
  u16* p; int tpos; float qs;
  if (item < 65536) { p = qb + item * 128; tpos = (item >> 4) & 2047; qs = 0.12751742f; }
  else { const int ik = item - 65536; p = kb + ik * 128; tpos = (ik >> 2) & 2047; qs = 1.0f; }
  const float f1 = b2f(p[l]);
  const float f2 = b2f(p[l + 64]);
  float ss = f1 * f1 + f2 * f2;
  #pragma unroll
  for (int d = 1; d < 64; d <<= 1) ss += __shfl_xor(ss, d);
  const float rn = rsqrtf(ss * (1.0f / 128.0f) + 1.1920928955078125e-07f);
  const float c = cost[tpos * 64 + l], s = sint[tpos * 64 + l];
  const float x1 = f1 * rn, x2 = f2 * rn;
  p[l]      = f2b((x1 * c + x2 * s) * qs);
  p[l + 64] = f2b((x2 * c - x1 * s) * qs);
}

// ---------------- causal GQA flash attention: no-max softmax + kv-split + ------------
// ---------------- exchange-free PV (vT token-permuted) -------------------------------
// grid (1024): bid&7 = (b,hkv) XCD-local; tau = 31-jj (longest first).
// Block = 64 q-rows (2 waves x 32 q). kv range split into two interleaved
// independent streams A/B (additive merge, m=0 softmax). PV B-fragments are the
// lane's own cvtpk'd P values (vT columns pre-permuted by token bit2<->3 swap).
__global__ __launch_bounds__(128) void k_attn(
    const u16* __restrict__ qb, const u16* __restrict__ kb,
    const u16* __restrict__ vT, float* __restrict__ out) {
  __shared__ __align__(16) char lds[65536];   // [buf][stream][K 8K | V 8K]
  const int tid = threadIdx.x;
  const int l = tid & 63;
  const int w = tid >> 6;          // wave 0/1 -> q offset 32*w
  const int lq = l & 31;
  const int hi = l >> 5;

  const int bid = blockIdx.x;
  const int cxc = bid & 7;
  const int bb  = cxc >> 2, hkv = cxc & 3;
  const int rest = bid >> 3;             // 0..127
  const int hsub = rest & 3, jj = rest >> 2;
  const int h   = hkv * 4 + hsub;
  const int tau = 31 - jj;               // 64-row q-tile index, longest first
  const int RH  = tau + 1;               // double-rounds (each = 2 kv-tiles of 32)
  const int half = RH * 32;              // stream B kv offset

  const u16* kbase = kb + ((size_t)bb * 2048) * 512 + hkv * 128;
  const u16* vbase = vT + ((size_t)(hkv * 128)) * 4096 + (size_t)bb * 2048;
  const u16* qhb   = qb + ((size_t)bb * 2048) * 2048 + h * 128;

  const int krow_t = tid >> 4, kch = tid & 15;   // K staging coords
  const int vrow_t = tid >> 2, vch = tid & 3;    // V staging coords

  const int qabs = tau * 64 + w * 32 + lq;
  const int qmin = tau * 64 + w * 32;

  bf16x8 qf[8];
  {
    const u16* qp = qhb + (size_t)qabs * 2048;
    #pragma unroll
    for (int c = 0; c < 8; ++c) qf[c] = *(const bf16x8*)(qp + c * 16 + hi * 8);
  }
  f32x16 oacc[4], sA, sB;
  #pragma unroll
  for (int dt = 0; dt < 4; ++dt)
    #pragma unroll
    for (int e = 0; e < 16; ++e) oacc[dt][e] = 0.f;
  float llA = 0.f, llB = 0.f;

  // stage one stream's kv-tile (16 KB: K 8K + V 8K), 128 threads x 8 gld16
  auto STAGE = [&](int buf, int st, int jb2) {
    char* bK = lds + buf * 32768 + st * 16384;
    char* bV = bK + 8192;
    #pragma unroll
    for (int u = 0; u < 4; ++u) {
      const int kr = u * 8 + krow_t;
      gld16(kbase + (size_t)(jb2 + kr) * 512 + ((kch ^ (kr & 15)) << 3),
            bK + u * 2048 + tid * 16);
      // V paired-row layout: slot (R0, C0) holds V[2*R0 + (cp>>2)][8*(cp&3) ..]
      const int R0 = u * 16 + (vrow_t >> 1);          // 0..63
      const int C0 = ((vrow_t & 1) << 2) + vch;       // 0..7
      const int cp = C0 ^ (R0 & 7);
      const int vd = 2 * R0 + (cp >> 2);              // d row 0..127
      gld16(vbase + (size_t)vd * 4096 + jb2 + ((cp & 3) << 3),
            bV + u * 2048 + tid * 16);
    }
  };

  STAGE(0, 0, 0);
  STAGE(0, 1, half);
  __syncthreads();

  int cur = 0;
  for (int r = 0; r < RH; ++r) {
    // prefetch next double-tile into the other buffer
    if (r + 1 < RH) {
      STAGE(cur ^ 1, 0, (r + 1) * 32);
      STAGE(cur ^ 1, 1, half + (r + 1) * 32);
    }

    // ---- QK^T for both streams (independent MFMA chains) ----
    #pragma unroll
    for (int e = 0; e < 16; ++e) { sA[e] = 0.f; sB[e] = 0.f; }
    const char* skA = lds + cur * 32768;
    const char* skB = skA + 16384;
    #pragma unroll
    for (int c = 0; c < 8; ++c) {
      const int ch = ((2 * c + hi) ^ (lq & 15)) << 4;
      const bf16x8 kfA = *(const bf16x8*)(skA + lq * 256 + ch);
      const bf16x8 kfB = *(const bf16x8*)(skB + lq * 256 + ch);
      sA = __builtin_amdgcn_mfma_f32_32x32x16_bf16(kfA, qf[c], sA, 0, 0, 0);
      sB = __builtin_amdgcn_mfma_f32_32x32x16_bf16(kfB, qf[c], sB, 0, 0, 0);
    }

    // ---- no-max softmax: p = exp2(s) (|s| <= 16.4 by RMS-norm bound) ----
    const int jbA = r * 32;
    const int jbB = half + r * 32;
    if (jbA + 31 > qmin) {
      #pragma unroll
      for (int e = 0; e < 16; ++e) {
        const int kvl = (e & 3) + ((e >> 2) << 3) + (hi << 2);
        if (jbA + kvl > qabs) sA[e] = -1e30f;
      }
    }
    if (jbB + 31 > qmin) {
      #pragma unroll
      for (int e = 0; e < 16; ++e) {
        const int kvl = (e & 3) + ((e >> 2) << 3) + (hi << 2);
        if (jbB + kvl > qabs) sB[e] = -1e30f;
      }
    }
    float rA = 0.f, rB = 0.f;
    #pragma unroll
    for (int e = 0; e < 16; e += 4) {
      const float a0 = exp2f(sA[e]),     a1 = exp2f(sA[e + 1]);
      const float a2 = exp2f(sA[e + 2]), a3 = exp2f(sA[e + 3]);
      const float b0 = exp2f(sB[e]),     b1 = exp2f(sB[e + 1]);
      const float b2 = exp2f(sB[e + 2]), b3 = exp2f(sB[e + 3]);
      sA[e] = a0; sA[e + 1] = a1; sA[e + 2] = a2; sA[e + 3] = a3;
      sB[e] = b0; sB[e + 1] = b1; sB[e + 2] = b2; sB[e + 3] = b3;
      rA += (a0 + a1) + (a2 + a3);
      rB += (b0 + b1) + (b2 + b3);
    }
    llA += rA; llB += rB;

    // ---- PV for both streams into shared oacc (additive merge) ----
    // Exchange-free: B-fragment = lane's own P values in order (vT pre-permuted).
    const char* svA = skA + 8192;
    const char* svB = skB + 8192;
    #pragma unroll
    for (int cc = 0; cc < 2; ++cc) {
      const int c8 = cc * 8;
      u32x4 bwA, bwB;
      bwA.x = cvtpk(sA[c8 + 0], sA[c8 + 1]);
      bwA.y = cvtpk(sA[c8 + 2], sA[c8 + 3]);
      bwA.z = cvtpk(sA[c8 + 4], sA[c8 + 5]);
      bwA.w = cvtpk(sA[c8 + 6], sA[c8 + 7]);
      bwB.x = cvtpk(sB[c8 + 0], sB[c8 + 1]);
      bwB.y = cvtpk(sB[c8 + 2], sB[c8 + 3]);
      bwB.z = cvtpk(sB[c8 + 4], sB[c8 + 5]);
      bwB.w = cvtpk(sB[c8 + 6], sB[c8 + 7]);
      const bf16x8 pfA = __builtin_bit_cast(bf16x8, bwA);
      const bf16x8 pfB = __builtin_bit_cast(bf16x8, bwB);
      #pragma unroll
      for (int dt = 0; dt < 4; ++dt) {
        const int vrow = dt * 16 + (lq >> 1);
        const int cpre = ((lq & 1) << 2) + 2 * cc + hi;
        const int chv = (cpre ^ (vrow & 7)) << 4;
        const bf16x8 vfA = *(const bf16x8*)(svA + vrow * 128 + chv);
        oacc[dt] = __builtin_amdgcn_mfma_f32_32x32x16_bf16(vfA, pfA, oacc[dt], 0, 0, 0);
      }
      #pragma unroll
      for (int dt = 0; dt < 4; ++dt) {
        const int vrow = dt * 16 + (lq >> 1);
        const int cpre = ((lq & 1) << 2) + 2 * cc + hi;
        const int chv = (cpre ^ (vrow & 7)) << 4;
        const bf16x8 vfB = *(const bf16x8*)(svB + vrow * 128 + chv);
        oacc[dt] = __builtin_amdgcn_mfma_f32_32x32x16_bf16(vfB, pfB, oacc[dt], 0, 0, 0);
      }
    }

    __syncthreads();
    cur ^= 1;
  }

  // ---- epilogue: merge streams + halves, write O ----
  float ll = llA + llB;
  ll += __shfl_xor(ll, 32);
  const float inv = 1.0f / ll;
  float* ob = out + ((size_t)(bb * 2048 + qabs)) * 2048 + h * 128;
  #pragma unroll
  for (int dt = 0; dt < 4; ++dt)
    #pragma unroll
    for (int qd = 0; qd < 4; ++qd) {
      float4 o4;
      o4.x = oacc[dt][qd * 4 + 0] * inv;
      o4.y = oacc[dt][qd * 4 + 1] * inv;
      o4.z = oacc[dt][qd * 4 + 2] * inv;
      o4.w = oacc[dt][qd * 4 + 3] * inv;
      *(float4*)(ob + dt * 32 + qd * 8 + hi * 4) = o4;
    }
}

extern "C" void kernel_launch(void* const* d_in, const int* in_sizes, int n_in,
                              void* d_out, int out_size, void* d_ws, size_t ws_size,
                              hipStream_t stream) {
  const float* x  = (const float*)d_in[0];
  const float* wq = (const float*)d_in[1];
  const float* wk = (const float*)d_in[2];
  const float* wv = (const float*)d_in[3];
  float* out = (float*)d_out;
  char* ws = (char*)d_ws;

  float* cost = (float*)(ws);                 // 512 KB
  float* sint = (float*)(ws + 524288);        // 512 KB
  u16* xb  = (u16*)(ws + 1048576);            // 16 MB
  u16* wqb = (u16*)(ws + 17825792);           // 8 MB
  u16* wkb = (u16*)(ws + 26214400);           // 2 MB
  u16* wvb = (u16*)(ws + 28311552);           // 2 MB
  u16* qb  = (u16*)(ws + 30408704);           // 16 MB
  u16* kb  = (u16*)(ws + 47185920);           // 4 MB
  u16* vT  = (u16*)(ws + 51380224);           // 4 MB  -> total 55574528
  if (ws_size < 55574528) return;

  k_tables  <<<dim3(512),   dim3(256), 0, stream>>>(cost, sint);
  k_convert <<<dim3(2048),  dim3(256), 0, stream>>>(x, wq, wk, wv, xb, wqb, wkb, wvb);
  k_gemm    <<<dim3(32, 24), dim3(256), 0, stream>>>(xb, wqb, wkb, wvb, qb, kb, vT);
  k_normrope<<<dim3(20480), dim3(256), 0, stream>>>(qb, kb, cost, sint);
  k_attn    <<<dim3(1024),  dim3(128), 0, stream>>>(qb, kb, vT, out);
}

// Round 11
// 163.972 us; speedup vs baseline: 1.2968x; 1.0256x over previous
//
#include <hip/hip_runtime.h>
#include <hip/hip_bf16.h>
#include <cstdint>

typedef __bf16 bf16x8 __attribute__((ext_vector_type(8)));
typedef float f32x4 __attribute__((ext_vector_type(4)));
typedef float f32x16 __attribute__((ext_vector_type(16)));
typedef unsigned int u32;
typedef unsigned short u16;
typedef u32 u32x4 __attribute__((ext_vector_type(4)));

#define AS1 __attribute__((address_space(1)))
#define AS3 __attribute__((address_space(3)))

static __device__ __forceinline__ void gld16(const void* g, void* l) {
  __builtin_amdgcn_global_load_lds((const AS1 u32*)g, (AS3 u32*)l, 16, 0, 0);
}
static __device__ __forceinline__ u16 f2b(float f) {
  return __builtin_bit_cast(u16, __float2bfloat16(f));
}
static __device__ __forceinline__ float b2f(u16 u) {
  return __bfloat162float(__builtin_bit_cast(__hip_bfloat16, u));
}
// one-instruction pack: lo = bf16(a), hi = bf16(b)
static __device__ __forceinline__ u32 cvtpk(float a, float b) {
  u32 r;
  asm("v_cvt_pk_bf16_f32 %0, %1, %2" : "=v"(r) : "v"(a), "v"(b));
  return r;
}

// ---------------- RoPE tables: cos/sin[t][i], t<2048, i<64 ----------------
__global__ void k_tables(float* __restrict__ cost, float* __restrict__ sint) {
  const int idx = blockIdx.x * 256 + threadIdx.x;   // 131072 total
  const int t = idx >> 6, i = idx & 63;
  const float inv = exp2f(-(float)(2 * i) * (13.287712379549449f / 128.0f));
  const float f = (float)t * inv;
  cost[idx] = cosf(f);
  sint[idx] = sinf(f);
}

// ---------------- fp32 -> bf16 convert of x, Wq, Wk, Wv ----------------
__global__ void k_convert(const float* __restrict__ x, const float* __restrict__ wq,
                          const float* __restrict__ wk, const float* __restrict__ wv,
                          u16* __restrict__ xb, u16* __restrict__ wqb,
                          u16* __restrict__ wkb, u16* __restrict__ wvb) {
  for (int i4 = blockIdx.x * blockDim.x + threadIdx.x; i4 < 3670016;
       i4 += gridDim.x * blockDim.x) {
    const int e = i4 * 4;
    const float* s; u16* d;
    if (e < 8388608)        { s = x  + e;              d = xb  + e; }
    else if (e < 12582912)  { int o = e - 8388608;  s = wq + o; d = wqb + o; }
    else if (e < 13631488)  { int o = e - 12582912; s = wk + o; d = wkb + o; }
    else                    { int o = e - 13631488; s = wv + o; d = wvb + o; }
    const float4 v = *(const float4*)s;
    ushort4 o4;
    o4.x = f2b(v.x); o4.y = f2b(v.y); o4.z = f2b(v.z); o4.w = f2b(v.w);
    *(ushort4*)d = o4;
  }
}

// ---------------- fused QKV projection GEMM (bf16 MFMA, m97 structure) ----------------
// vT is written with token-index bits 2<->3 swapped (within each 16-token group):
// makes attention's PV B-fragment equal the lane's OWN softmax values (no shfl).
__global__ __launch_bounds__(256) void k_gemm(
    const u16* __restrict__ xb, const u16* __restrict__ wqb,
    const u16* __restrict__ wkb, const u16* __restrict__ wvb,
    u16* __restrict__ qb, u16* __restrict__ kb, u16* __restrict__ vT) {
  __shared__ __align__(16) char smA[8192];   // [128][32] bf16, source-chunk-swizzled
  __shared__ __align__(16) char smB[8192];
  const int tid = threadIdx.x;
  const int w = tid >> 6, l = tid & 63;
  const int lm = l & 15, g = l >> 4;
  const int m0 = blockIdx.x << 7;
  const int j = blockIdx.y;
  const u16* W; u16* dst; int n0, ldc, vmode;
  if (j < 16)      { W = wqb; dst = qb; n0 = j << 7;        ldc = 2048; vmode = 0; }
  else if (j < 20) { W = wkb; dst = kb; n0 = (j - 16) << 7; ldc = 512;  vmode = 0; }
  else             { W = wvb; dst = vT; n0 = (j - 20) << 7; ldc = 0;    vmode = 1; }

  const int srow = w * 16 + (l >> 2);
  const int scol = l & 3;

  f32x4 acc[4][4];
  #pragma unroll
  for (int a = 0; a < 4; ++a)
    #pragma unroll
    for (int bb = 0; bb < 4; ++bb) { f32x4 zz = {0.f, 0.f, 0.f, 0.f}; acc[a][bb] = zz; }

  const int wm = (w >> 1) << 6, wn = (w & 1) << 6;

  for (int k0 = 0; k0 < 2048; k0 += 32) {
    #pragma unroll
    for (int i = 0; i < 2; ++i) {
      const int r = srow + (i << 6);
      const int sc = (scol ^ (r & 3)) << 3;
      gld16(xb + (m0 + r) * 2048 + k0 + sc, smA + ((i * 4 + w) << 10));
      gld16(W  + (n0 + r) * 2048 + k0 + sc, smB + ((i * 4 + w) << 10));
    }
    __syncthreads();
    bf16x8 af[4], bfr[4];
    #pragma unroll
    for (int mt = 0; mt < 4; ++mt) {
      const int row = wm + mt * 16 + lm;
      af[mt] = *(const bf16x8*)(smA + row * 64 + ((g ^ (row & 3)) << 4));
    }
    #pragma unroll
    for (int nt = 0; nt < 4; ++nt) {
      const int row = wn + nt * 16 + lm;
      bfr[nt] = *(const bf16x8*)(smB + row * 64 + ((g ^ (row & 3)) << 4));
    }
    #pragma unroll
    for (int mt = 0; mt < 4; ++mt)
      #pragma unroll
      for (int nt = 0; nt < 4; ++nt)
        acc[mt][nt] = __builtin_amdgcn_mfma_f32_16x16x32_bf16(af[mt], bfr[nt], acc[mt][nt], 0, 0, 0);
    __syncthreads();
  }

  const int gs = ((g & 1) << 1) | (g >> 1);   // token-index bit2<->bit3 swap for vT
  #pragma unroll
  for (int mt = 0; mt < 4; ++mt) {
    #pragma unroll
    for (int nt = 0; nt < 4; ++nt) {
      const int n = n0 + wn + nt * 16 + lm;
      #pragma unroll
      for (int r = 0; r < 4; ++r) {
        const u16 hv = f2b(acc[mt][nt][r]);
        if (!vmode) {
          const int mq = m0 + wm + mt * 16 + g * 4 + r;
          dst[mq * ldc + n] = hv;
        } else {
          const int mv = m0 + wm + mt * 16 + gs * 4 + r;
          dst[n * 4096 + mv] = hv;
        }
      }
    }
  }
}

// ---------------- RMSNorm + RoPE in-place on q and k ----------------
// q additionally pre-scaled by log2(e)/sqrt(128) so attention skips the scale.
// Consequence: attention scores s in [-16.4, 16.4] -> no online max needed.
__global__ __launch_bounds__(256) void k_normrope(u16* __restrict__ qb, u16* __restrict__ kb,
                                                  const float* __restrict__ cost,
                                                  const float* __restrict__ sint) {
  const int item = blockIdx.x * 4 + (threadIdx.x >> 6);
  const int l = threadIdx.x & 63;
  u16* p; int tpos; float qs;
  if (item < 65536) { p = qb + item * 128; tpos = (item >> 4) & 2047; qs = 0.12751742f; }
  else { const int ik = item - 65536; p = kb + ik * 128; tpos = (ik >> 2) & 2047; qs = 1.0f; }
  const float f1 = b2f(p[l]);
  const float f2 = b2f(p[l + 64]);
  float ss = f1 * f1 + f2 * f2;
  #pragma unroll
  for (int d = 1; d < 64; d <<= 1) ss += __shfl_xor(ss, d);
  const float rn = rsqrtf(ss * (1.0f / 128.0f) + 1.1920928955078125e-07f);
  const float c = cost[tpos * 64 + l], s = sint[tpos * 64 + l];
  const float x1 = f1 * rn, x2 = f2 * rn;
  p[l]      = f2b((x1 * c + x2 * s) * qs);
  p[l + 64] = f2b((x2 * c - x1 * s) * qs);
}

// ---------------- causal GQA flash attention: no-max softmax + kv-split, -------------
// ---------------- SINGLE-buffer 32KB LDS -> 4 blocks/CU (2 indep waves/SIMD) ---------
// grid (1024): bid&7 = (b,hkv) XCD-local. g = bid>>5 in [0,32), a = g&7.
// Ring-complementary tau map: ring0 31-a, ring1 16+a, ring2 15-a, ring3 a ->
// each CU's 4 resident blocks {bid, +256, +512, +768} sum to exactly 66
// double-rounds (balanced), longest dispatched first.
// Block = 64 q-rows (2 waves x 32 q). kv range split into two interleaved
// independent streams A/B (additive merge, m=0 softmax). PV B-fragments are the
// lane's own cvtpk'd P values (vT columns pre-permuted by token bit2<->3 swap).
__global__ __launch_bounds__(128) void k_attn(
    const u16* __restrict__ qb, const u16* __restrict__ kb,
    const u16* __restrict__ vT, float* __restrict__ out) {
  __shared__ __align__(16) char lds[32768];   // [stream][K 8K | V 8K]
  const int tid = threadIdx.x;
  const int l = tid & 63;
  const int w = tid >> 6;          // wave 0/1 -> q offset 32*w
  const int lq = l & 31;
  const int hi = l >> 5;

  const int bid = blockIdx.x;
  const int cxc = bid & 7;
  const int bb  = cxc >> 2, hkv = cxc & 3;
  const int hsub = (bid >> 3) & 3;
  const int h   = hkv * 4 + hsub;
  const int g   = bid >> 5;              // 0..31, ring = g>>3
  const int a   = g & 7;
  const int tau = (g < 8) ? (31 - a) : (g < 16) ? (16 + a) : (g < 24) ? (15 - a) : a;
  const int RH  = tau + 1;               // double-rounds (each = 2 kv-tiles of 32)
  const int half = RH * 32;              // stream B kv offset

  const u16* kbase = kb + ((size_t)bb * 2048) * 512 + hkv * 128;
  const u16* vbase = vT + ((size_t)(hkv * 128)) * 4096 + (size_t)bb * 2048;
  const u16* qhb   = qb + ((size_t)bb * 2048) * 2048 + h * 128;

  const int krow_t = tid >> 4, kch = tid & 15;   // K staging coords
  const int vrow_t = tid >> 2, vch = tid & 3;    // V staging coords

  const int qabs = tau * 64 + w * 32 + lq;
  const int qmin = tau * 64 + w * 32;

  bf16x8 qf[8];
  {
    const u16* qp = qhb + (size_t)qabs * 2048;
    #pragma unroll
    for (int c = 0; c < 8; ++c) qf[c] = *(const bf16x8*)(qp + c * 16 + hi * 8);
  }
  f32x16 oacc[4], sA, sB;
  #pragma unroll
  for (int dt = 0; dt < 4; ++dt)
    #pragma unroll
    for (int e = 0; e < 16; ++e) oacc[dt][e] = 0.f;
  float llA = 0.f, llB = 0.f;

  // stage one stream's kv-tile (16 KB: K 8K + V 8K), 128 threads x 8 gld16
  auto STAGE = [&](int st, int jb2) {
    char* bK = lds + st * 16384;
    char* bV = bK + 8192;
    #pragma unroll
    for (int u = 0; u < 4; ++u) {
      const int kr = u * 8 + krow_t;
      gld16(kbase + (size_t)(jb2 + kr) * 512 + ((kch ^ (kr & 15)) << 3),
            bK + u * 2048 + tid * 16);
      // V paired-row layout: slot (R0, C0) holds V[2*R0 + (cp>>2)][8*(cp&3) ..]
      const int R0 = u * 16 + (vrow_t >> 1);          // 0..63
      const int C0 = ((vrow_t & 1) << 2) + vch;       // 0..7
      const int cp = C0 ^ (R0 & 7);
      const int vd = 2 * R0 + (cp >> 2);              // d row 0..127
      gld16(vbase + (size_t)vd * 4096 + jb2 + ((cp & 3) << 3),
            bV + u * 2048 + tid * 16);
    }
  };

  STAGE(0, 0);
  STAGE(1, half);
  __syncthreads();

  for (int r = 0; r < RH; ++r) {
    // ---- QK^T for both streams (independent MFMA chains) ----
    #pragma unroll
    for (int e = 0; e < 16; ++e) { sA[e] = 0.f; sB[e] = 0.f; }
    const char* skA = lds;
    const char* skB = lds + 16384;
    #pragma unroll
    for (int c = 0; c < 8; ++c) {
      const int ch = ((2 * c + hi) ^ (lq & 15)) << 4;
      const bf16x8 kfA = *(const bf16x8*)(skA + lq * 256 + ch);
      const bf16x8 kfB = *(const bf16x8*)(skB + lq * 256 + ch);
      sA = __builtin_amdgcn_mfma_f32_32x32x16_bf16(kfA, qf[c], sA, 0, 0, 0);
      sB = __builtin_amdgcn_mfma_f32_32x32x16_bf16(kfB, qf[c], sB, 0, 0, 0);
    }

    // ---- no-max softmax: p = exp2(s) (|s| <= 16.4 by RMS-norm bound) ----
    const int jbA = r * 32;
    const int jbB = half + r * 32;
    if (jbA + 31 > qmin) {
      #pragma unroll
      for (int e = 0; e < 16; ++e) {
        const int kvl = (e & 3) + ((e >> 2) << 3) + (hi << 2);
        if (jbA + kvl > qabs) sA[e] = -1e30f;
      }
    }
    if (jbB + 31 > qmin) {
      #pragma unroll
      for (int e = 0; e < 16; ++e) {
        const int kvl = (e & 3) + ((e >> 2) << 3) + (hi << 2);
        if (jbB + kvl > qabs) sB[e] = -1e30f;
      }
    }
    float rA = 0.f, rB = 0.f;
    #pragma unroll
    for (int e = 0; e < 16; e += 4) {
      const float a0 = exp2f(sA[e]),     a1 = exp2f(sA[e + 1]);
      const float a2 = exp2f(sA[e + 2]), a3 = exp2f(sA[e + 3]);
      const float b0 = exp2f(sB[e]),     b1 = exp2f(sB[e + 1]);
      const float b2 = exp2f(sB[e + 2]), b3 = exp2f(sB[e + 3]);
      sA[e] = a0; sA[e + 1] = a1; sA[e + 2] = a2; sA[e + 3] = a3;
      sB[e] = b0; sB[e + 1] = b1; sB[e + 2] = b2; sB[e + 3] = b3;
      rA += (a0 + a1) + (a2 + a3);
      rB += (b0 + b1) + (b2 + b3);
    }
    llA += rA; llB += rB;

    // ---- PV for both streams into shared oacc (additive merge) ----
    // Exchange-free: B-fragment = lane's own P values in order (vT pre-permuted).
    const char* svA = lds + 8192;
    const char* svB = lds + 16384 + 8192;
    #pragma unroll
    for (int cc = 0; cc < 2; ++cc) {
      const int c8 = cc * 8;
      u32x4 bwA, bwB;
      bwA.x = cvtpk(sA[c8 + 0], sA[c8 + 1]);
      bwA.y = cvtpk(sA[c8 + 2], sA[c8 + 3]);
      bwA.z = cvtpk(sA[c8 + 4], sA[c8 + 5]);
      bwA.w = cvtpk(sA[c8 + 6], sA[c8 + 7]);
      bwB.x = cvtpk(sB[c8 + 0], sB[c8 + 1]);
      bwB.y = cvtpk(sB[c8 + 2], sB[c8 + 3]);
      bwB.z = cvtpk(sB[c8 + 4], sB[c8 + 5]);
      bwB.w = cvtpk(sB[c8 + 6], sB[c8 + 7]);
      const bf16x8 pfA = __builtin_bit_cast(bf16x8, bwA);
      const bf16x8 pfB = __builtin_bit_cast(bf16x8, bwB);
      #pragma unroll
      for (int dt = 0; dt < 4; ++dt) {
        const int vrow = dt * 16 + (lq >> 1);
        const int cpre = ((lq & 1) << 2) + 2 * cc + hi;
        const int chv = (cpre ^ (vrow & 7)) << 4;
        const bf16x8 vfA = *(const bf16x8*)(svA + vrow * 128 + chv);
        oacc[dt] = __builtin_amdgcn_mfma_f32_32x32x16_bf16(vfA, pfA, oacc[dt], 0, 0, 0);
      }
      #pragma unroll
      for (int dt = 0; dt < 4; ++dt) {
        const int vrow = dt * 16 + (lq >> 1);
        const int cpre = ((lq & 1) << 2) + 2 * cc + hi;
        const int chv = (cpre ^ (vrow & 7)) << 4;
        const bf16x8 vfB = *(const bf16x8*)(svB + vrow * 128 + chv);
        oacc[dt] = __builtin_amdgcn_mfma_f32_32x32x16_bf16(vfB, pfB, oacc[dt], 0, 0, 0);
      }
    }

    // ---- restage (single buffer): wait for readers, stage, wait for data ----
    if (r + 1 < RH) {
      __syncthreads();                 // all waves done reading this round
      STAGE(0, (r + 1) * 32);
      STAGE(1, half + (r + 1) * 32);
      __syncthreads();                 // vmcnt(0) drain + visibility
    }
  }

  // ---- epilogue: merge streams + halves, write O ----
  float ll = llA + llB;
  ll += __shfl_xor(ll, 32);
  const float inv = 1.0f / ll;
  float* ob = out + ((size_t)(bb * 2048 + qabs)) * 2048 + h * 128;
  #pragma unroll
  for (int dt = 0; dt < 4; ++dt)
    #pragma unroll
    for (int qd = 0; qd < 4; ++qd) {
      float4 o4;
      o4.x = oacc[dt][qd * 4 + 0] * inv;
      o4.y = oacc[dt][qd * 4 + 1] * inv;
      o4.z = oacc[dt][qd * 4 + 2] * inv;
      o4.w = oacc[dt][qd * 4 + 3] * inv;
      *(float4*)(ob + dt * 32 + qd * 8 + hi * 4) = o4;
    }
}

extern "C" void kernel_launch(void* const* d_in, const int* in_sizes, int n_in,
                              void* d_out, int out_size, void* d_ws, size_t ws_size,
                              hipStream_t stream) {
  const float* x  = (const float*)d_in[0];
  const float* wq = (const float*)d_in[1];
  const float* wk = (const float*)d_in[2];
  const float* wv = (const float*)d_in[3];
  float* out = (float*)d_out;
  char* ws = (char*)d_ws;

  float* cost = (float*)(ws);                 // 512 KB
  float* sint = (float*)(ws + 524288);        // 512 KB
  u16* xb  = (u16*)(ws + 1048576);            // 16 MB
  u16* wqb = (u16*)(ws + 17825792);           // 8 MB
  u16* wkb = (u16*)(ws + 26214400);           // 2 MB
  u16* wvb = (u16*)(ws + 28311552);           // 2 MB
  u16* qb  = (u16*)(ws + 30408704);           // 16 MB
  u16* kb  = (u16*)(ws + 47185920);           // 4 MB
  u16* vT  = (u16*)(ws + 51380224);           // 4 MB  -> total 55574528
  if (ws_size < 55574528) return;

  k_tables  <<<dim3(512),   dim3(256), 0, stream>>>(cost, sint);
  k_convert <<<dim3(2048),  dim3(256), 0, stream>>>(x, wq, wk, wv, xb, wqb, wkb, wvb);
  k_gemm    <<<dim3(32, 24), dim3(256), 0, stream>>>(xb, wqb, wkb, wvb, qb, kb, vT);
  k_normrope<<<dim3(20480), dim3(256), 0, stream>>>(qb, kb, cost, sint);
  k_attn    <<<dim3(1024),  dim3(128), 0, stream>>>(qb, kb, vT, out);
}